// Round 7
// baseline (458.478 us; speedup 1.0000x reference)
//
#include <hip/hip_runtime.h>
#include <math.h>

#define NB 4
#define TT 1024
#define DD 1024
#define NTOK 4096
#define ND (NTOK*DD)

typedef __attribute__((ext_vector_type(8))) short bh8;
typedef __attribute__((ext_vector_type(4))) float fx4;

__device__ __forceinline__ unsigned short f2bf(float f) {
    unsigned int b = __float_as_uint(f);
    b += 0x7fffu + ((b >> 16) & 1u);
    return (unsigned short)(b >> 16);
}

// pack two fp32 -> packed bf16 (RNE); HW v_cvt_pk_bf16_f32 when available
__device__ __forceinline__ unsigned pkbf(float a, float b) {
#if __has_builtin(__builtin_amdgcn_cvt_pk_bf16_f32)
    auto r = __builtin_amdgcn_cvt_pk_bf16_f32(a, b);
    unsigned u;
    __builtin_memcpy(&u, &r, 4);
    return u;
#else
    return ((unsigned)f2bf(b) << 16) | f2bf(a);
#endif
}

// async global->LDS, 16B per lane, LDS dst = wave-uniform base + lane*16
#define GLD16(gp, lp) __builtin_amdgcn_global_load_lds( \
    (__attribute__((address_space(1))) void*)(gp), \
    (__attribute__((address_space(3))) void*)(lp), 16, 0, 0)

// ---------- fused preprocessing: 5x wconv, w1T, dw1T, w2T ----------
__global__ __launch_bounds__(256) void k_prep(const float* __restrict__ W_r, const float* __restrict__ W_k,
                                              const float* __restrict__ W_v, const float* __restrict__ W_g,
                                              const float* __restrict__ W_o,
                                              const float* __restrict__ w1, const float* __restrict__ dw1,
                                              const float* __restrict__ w2,
                                              unsigned short* __restrict__ Wrb, unsigned short* __restrict__ Wkb,
                                              unsigned short* __restrict__ Wvb, unsigned short* __restrict__ Wgb,
                                              unsigned short* __restrict__ Wob,
                                              unsigned short* __restrict__ w1T, unsigned short* __restrict__ dw1T,
                                              unsigned short* __restrict__ w2T16) {
    int y = blockIdx.y, bx = blockIdx.x, tid = threadIdx.x;   // grid (640, 7)
    if (y < 5) {
        if (bx >= 512) return;
        const float* s = (y == 0) ? W_r : (y == 1) ? W_k : (y == 2) ? W_v : (y == 3) ? W_g : W_o;
        unsigned short* d = (y == 0) ? Wrb : (y == 1) ? Wkb : (y == 2) ? Wvb : (y == 3) ? Wgb : Wob;
        int i = (bx * 256 + tid) * 8;
        float4 a = *(const float4*)(s + i);
        float4 b = *(const float4*)(s + i + 4);
        uint4 o;
        o.x = pkbf(a.x, a.y);
        o.y = pkbf(a.z, a.w);
        o.z = pkbf(b.x, b.y);
        o.w = pkbf(b.z, b.w);
        *(uint4*)(d + i) = o;
    } else if (y == 5) {
        int o = bx * 256 + tid;          // 163840 total
        int r = o & 1023, c = o >> 10;
        w1T[o] = f2bf(w1[r * 160 + c]);
    } else {
        if (bx < 256) {
            int o = bx * 256 + tid;      // 65536 total
            int r = o & 1023, c = o >> 10;
            dw1T[o] = f2bf(dw1[r * 64 + c]);
        } else if (bx < 276) {
            int wi = bx - 256;
            int f = wi >> 2;
            int d = (wi & 3) * 256 + tid;
#pragma unroll 8
            for (int m = 0; m < 32; m++)
                w2T16[(size_t)(f * 1024 + d) * 32 + m] = f2bf(w2[(size_t)(f * 32 + m) * 1024 + d]);
        }
    }
}

// ---------- k2: xxx16 = bf16(tanh(xmix @ w1)), xmix computed in-reg ----------
__global__ __launch_bounds__(64) void k_xxx2(const float* __restrict__ x,
                                             const float* __restrict__ maa_x,
                                             const unsigned short* __restrict__ w1T,
                                             unsigned short* __restrict__ xxx16) {
    int lane = threadIdx.x;
    int l15 = lane & 15, qd = lane >> 4;
    int m0 = blockIdx.x * 16;    // grid 256
    int tok = m0 + l15;
    int t = tok & 1023;
    bool hasm = (t > 0), hasp = (t < 1023);
    const float* xr = x + (size_t)tok * 1024;
    fx4 acc[10];
#pragma unroll
    for (int nt = 0; nt < 10; nt++)
#pragma unroll
        for (int r = 0; r < 4; r++) acc[nt][r] = 0.f;
    const float4 z4 = make_float4(0.f, 0.f, 0.f, 0.f);
#pragma unroll 2
    for (int kb = 0; kb < 1024; kb += 32) {
        int k8 = kb + qd * 8;
        float4 c0 = *(const float4*)(xr + k8);
        float4 c1 = *(const float4*)(xr + k8 + 4);
        float4 m0v = hasm ? *(const float4*)(xr - 1024 + k8)     : z4;
        float4 m1v = hasm ? *(const float4*)(xr - 1024 + k8 + 4) : z4;
        float4 p0v = hasp ? *(const float4*)(xr + 1024 + k8)     : z4;
        float4 p1v = hasp ? *(const float4*)(xr + 1024 + k8 + 4) : z4;
        float4 a0 = *(const float4*)(maa_x + k8);
        float4 a1 = *(const float4*)(maa_x + k8 + 4);
        float v0 = c0.x + (0.5f * (m0v.x + p0v.x) - c0.x) * a0.x;
        float v1 = c0.y + (0.5f * (m0v.y + p0v.y) - c0.y) * a0.y;
        float v2 = c0.z + (0.5f * (m0v.z + p0v.z) - c0.z) * a0.z;
        float v3 = c0.w + (0.5f * (m0v.w + p0v.w) - c0.w) * a0.w;
        float v4 = c1.x + (0.5f * (m1v.x + p1v.x) - c1.x) * a1.x;
        float v5 = c1.y + (0.5f * (m1v.y + p1v.y) - c1.y) * a1.y;
        float v6 = c1.z + (0.5f * (m1v.z + p1v.z) - c1.z) * a1.z;
        float v7 = c1.w + (0.5f * (m1v.w + p1v.w) - c1.w) * a1.w;
        union { unsigned u[4]; bh8 h; } af;
        af.u[0] = pkbf(v0, v1);
        af.u[1] = pkbf(v2, v3);
        af.u[2] = pkbf(v4, v5);
        af.u[3] = pkbf(v6, v7);
#pragma unroll
        for (int nt = 0; nt < 10; nt++) {
            bh8 bf = *(const bh8*)(w1T + (size_t)(nt * 16 + l15) * 1024 + kb + qd * 8);
            acc[nt] = __builtin_amdgcn_mfma_f32_16x16x32_bf16(af.h, bf, acc[nt], 0, 0, 0);
        }
    }
#pragma unroll
    for (int nt = 0; nt < 10; nt++)
#pragma unroll
        for (int r = 0; r < 4; r++)
            xxx16[(size_t)(m0 + qd * 4 + r) * 160 + nt * 16 + l15] = f2bf(tanhf(acc[nt][r]));
}

// ---------- k3: fused mm-einsum (MFMA, K=32) + five mixes, no LDS ----------
__global__ __launch_bounds__(256, 2) void k_mmix(const float* __restrict__ x,
                                                 const unsigned short* __restrict__ xxx16,
                                                 const unsigned short* __restrict__ w2T16,
                                                 const float* __restrict__ maa_w,
                                                 const float* __restrict__ maa_k,
                                                 const float* __restrict__ maa_v,
                                                 const float* __restrict__ maa_r,
                                                 const float* __restrict__ maa_g,
                                                 unsigned short* __restrict__ xw16,
                                                 unsigned short* __restrict__ xk16,
                                                 unsigned short* __restrict__ xv16,
                                                 unsigned short* __restrict__ xr16,
                                                 unsigned short* __restrict__ xg16) {
    int tid = threadIdx.x;
    int w = tid >> 6, lane = tid & 63, l15 = lane & 15, qd = lane >> 4;
    int n0 = blockIdx.x * 64;               // grid (16, 32)
    int m0w = blockIdx.y * 128 + w * 32;
    const float* maap[5] = {maa_w, maa_k, maa_v, maa_r, maa_g};
    unsigned short* outp[5] = {xw16, xk16, xv16, xr16, xg16};
    float xin[8][4], dxv[8][4];
#pragma unroll
    for (int mi = 0; mi < 2; mi++)
#pragma unroll
        for (int r = 0; r < 4; r++) {
            int tok = m0w + mi * 16 + qd * 4 + r;
            int t = tok & 1023;
#pragma unroll
            for (int ni = 0; ni < 4; ni++) {
                int d = n0 + ni * 16 + l15;
                size_t idx = (size_t)tok * 1024 + d;
                float xv = x[idx];
                float xm1 = (t > 0)    ? x[idx - 1024] : 0.f;
                float xp1 = (t < 1023) ? x[idx + 1024] : 0.f;
                xin[mi * 4 + r][ni] = xv;
                dxv[mi * 4 + r][ni] = 0.5f * (xm1 + xp1) - xv;
            }
        }
#pragma unroll
    for (int f = 0; f < 5; f++) {
        bh8 af[2], bf[4];
#pragma unroll
        for (int mi = 0; mi < 2; mi++)
            af[mi] = *(const bh8*)(xxx16 + (size_t)(m0w + mi * 16 + l15) * 160 + f * 32 + qd * 8);
#pragma unroll
        for (int ni = 0; ni < 4; ni++)
            bf[ni] = *(const bh8*)(w2T16 + (size_t)(f * 1024 + n0 + ni * 16 + l15) * 32 + qd * 8);
        fx4 acc[2][4];
#pragma unroll
        for (int mi = 0; mi < 2; mi++)
#pragma unroll
            for (int ni = 0; ni < 4; ni++) {
#pragma unroll
                for (int r = 0; r < 4; r++) acc[mi][ni][r] = 0.f;
                acc[mi][ni] = __builtin_amdgcn_mfma_f32_16x16x32_bf16(af[mi], bf[ni], acc[mi][ni], 0, 0, 0);
            }
        const float* maa = maap[f];
        unsigned short* op = outp[f];
#pragma unroll
        for (int ni = 0; ni < 4; ni++) {
            float mv = maa[n0 + ni * 16 + l15];
#pragma unroll
            for (int mi = 0; mi < 2; mi++)
#pragma unroll
                for (int r = 0; r < 4; r++) {
                    float o = xin[mi * 4 + r][ni] + dxv[mi * 4 + r][ni] * (mv + acc[mi][ni][r]);
                    op[(size_t)(m0w + mi * 16 + qd * 4 + r) * 1024 + n0 + ni * 16 + l15] = f2bf(o);
                }
        }
    }
}

// ---------- decay GEMM1 via MFMA: dech = tanh(xw @ dw1), 1-wave blocks ----------
__global__ __launch_bounds__(64) void k_dec1m(const unsigned short* __restrict__ xw16,
                                              const unsigned short* __restrict__ dw1T,
                                              float* __restrict__ dech) {
    int lane = threadIdx.x;
    int l15 = lane & 15, qd = lane >> 4;
    int m0 = blockIdx.x * 16;    // grid 256
    fx4 acc[4];
#pragma unroll
    for (int nt = 0; nt < 4; nt++)
#pragma unroll
        for (int r = 0; r < 4; r++) acc[nt][r] = 0.f;
#pragma unroll 2
    for (int kb = 0; kb < 1024; kb += 32) {
        bh8 af = *(const bh8*)(xw16 + (size_t)(m0 + l15) * 1024 + kb + qd * 8);
#pragma unroll
        for (int nt = 0; nt < 4; nt++) {
            bh8 bf = *(const bh8*)(dw1T + (size_t)(nt * 16 + l15) * 1024 + kb + qd * 8);
            acc[nt] = __builtin_amdgcn_mfma_f32_16x16x32_bf16(af, bf, acc[nt], 0, 0, 0);
        }
    }
#pragma unroll
    for (int nt = 0; nt < 4; nt++)
#pragma unroll
        for (int r = 0; r < 4; r++)
            dech[(size_t)(m0 + qd * 4 + r) * 64 + nt * 16 + l15] = tanhf(acc[nt][r]);
}

// ---------- decay GEMM2: ew = -exp(time_decay + dech @ dw2) ----------
__global__ __launch_bounds__(256) void k_dec2(const float* __restrict__ dech,
                                              const float* __restrict__ dw2,
                                              const float* __restrict__ tdec,
                                              float* __restrict__ ew) {
    __shared__ float hl[8][64];
    int tid = threadIdx.x;
    int tok0 = blockIdx.x * 8;     // grid 512
    {
        int l = tid;        hl[l >> 6][l & 63] = dech[tok0 * 64 + l];
        l = tid + 256;      hl[l >> 6][l & 63] = dech[tok0 * 64 + l];
    }
    __syncthreads();
#pragma unroll 1
    for (int c = 0; c < 4; c++) {
        int d = c * 256 + tid;
        float acc[8] = {};
#pragma unroll 8
        for (int j = 0; j < 64; j++) {
            float wv = dw2[j * 1024 + d];
#pragma unroll
            for (int g = 0; g < 8; g++) acc[g] = fmaf(hl[g][j], wv, acc[g]);
        }
        float td = tdec[d];
#pragma unroll
        for (int g = 0; g < 8; g++) ew[(tok0 + g) * 1024 + d] = -expf(td + acc[g]);
    }
}

// ---------- scan stage 1: per-segment sums (seg = 32) ----------
__global__ __launch_bounds__(64) void k_scan1(const float* __restrict__ ew, float* __restrict__ segsum) {
    int bx = blockIdx.x;            // grid 2048 = 4b x 32seg x 16dch
    int b = bx >> 9, seg = (bx >> 4) & 31, dch = bx & 15;
    int d = dch * 64 + threadIdx.x;
    size_t base = ((size_t)(b * 1024 + seg * 32)) * 1024 + d;
    float s = 0.f;
#pragma unroll 8
    for (int t = 0; t < 32; t++) s += ew[base + (size_t)t * 1024];
    segsum[(b * 32 + seg) * 1024 + d] = s;
}

// ---------- scan stage 2+3 fused: local prefix of segsums + emit clipped cf/cb ----------
__global__ __launch_bounds__(64) void k_scan3(const float* __restrict__ ew, const float* __restrict__ segsum,
                                              float* __restrict__ cf, float* __restrict__ cb) {
    int bx = blockIdx.x;            // grid 2048
    int b = bx >> 9, seg = (bx >> 4) & 31, dch = bx & 15;
    int d = dch * 64 + threadIdx.x;
    float run = 0.f, pre = 0.f, off16 = 0.f;
#pragma unroll
    for (int s = 0; s < 32; s++) {
        float tv = segsum[(b * 32 + s) * 1024 + d];
        if (s == seg) pre = run;
        if (s == 16) off16 = run;
        run += tv;
    }
    float e512 = ew[((size_t)(b * 1024 + 512)) * 1024 + d];
    float sb = off16;           // cs[511]
    float sf = off16 + e512;    // cs[512]
    float cum = pre;
    size_t base = ((size_t)(b * 1024 + seg * 32)) * 1024 + d;
#pragma unroll 4
    for (int t = 0; t < 32; t++) {
        float prev = cum;
        cum += ew[base + (size_t)t * 1024];
        cf[base + (size_t)t * 1024] = fminf(fmaxf(cum - sf, -60.f), 60.f);
        cb[base + (size_t)t * 1024] = fminf(fmaxf(prev - sb, -60.f), 60.f);
    }
}

// ---------- bf16 MFMA GEMM core: C[4096][1024] = A @ W^T, async LDS staging ----------
// modes: 0 fp32 out, 1 silu fp32, 2 q-exp (O1=qf,O2=qb), 3 k-exp (O1=kf,O2=kb), 4 v-transpose (O1=vvt)
__device__ __forceinline__ void gemm_body(const unsigned short* __restrict__ A,
                                          const unsigned short* __restrict__ W,
                                          int m0, int n0, int mode,
                                          float* __restrict__ Cf,
                                          unsigned short* __restrict__ O1,
                                          unsigned short* __restrict__ O2,
                                          const float* __restrict__ cfp,
                                          const float* __restrict__ cbp,
                                          char* smem) {
    int tid = threadIdx.x;
    int w = tid >> 6, lane = tid & 63, l15 = lane & 15, qd = lane >> 4;
    int wm = w >> 1, wn = w & 1;
    fx4 acc[4][4];
#pragma unroll
    for (int mt = 0; mt < 4; mt++)
#pragma unroll
        for (int nt = 0; nt < 4; nt++)
#pragma unroll
            for (int r = 0; r < 4; r++) acc[mt][nt][r] = 0.f;
    unsigned short* sA = (unsigned short*)smem;            // [128][32]
    unsigned short* sB = (unsigned short*)(smem + 8192);   // [128][32]
    int rowA = tid >> 2, cA = tid & 3;
    for (int kb = 0; kb < 1024; kb += 32) {
        __syncthreads();
        GLD16(A + (size_t)(m0 + rowA) * 1024 + kb + cA * 8,      sA + w * 512);
        GLD16(A + (size_t)(m0 + 64 + rowA) * 1024 + kb + cA * 8, sA + 2048 + w * 512);
        GLD16(W + (size_t)(n0 + rowA) * 1024 + kb + cA * 8,      sB + w * 512);
        GLD16(W + (size_t)(n0 + 64 + rowA) * 1024 + kb + cA * 8, sB + 2048 + w * 512);
        __syncthreads();
        bh8 af[4], bfr[4];
#pragma unroll
        for (int mt = 0; mt < 4; mt++)
            af[mt] = *(const bh8*)(sA + (wm * 64 + mt * 16 + l15) * 32 + qd * 8);
#pragma unroll
        for (int nt = 0; nt < 4; nt++)
            bfr[nt] = *(const bh8*)(sB + (wn * 64 + nt * 16 + l15) * 32 + qd * 8);
#pragma unroll
        for (int mt = 0; mt < 4; mt++)
#pragma unroll
            for (int nt = 0; nt < 4; nt++)
                acc[mt][nt] = __builtin_amdgcn_mfma_f32_16x16x32_bf16(af[mt], bfr[nt], acc[mt][nt], 0, 0, 0);
    }
    int mb = m0 + wm * 64, nb = n0 + wn * 64;
    if (mode <= 1) {
#pragma unroll
        for (int mt = 0; mt < 4; mt++)
#pragma unroll
            for (int nt = 0; nt < 4; nt++) {
                fx4 s = acc[mt][nt];
#pragma unroll
                for (int r = 0; r < 4; r++) {
                    float v = s[r];
                    if (mode == 1) v = v / (1.f + __expf(-v));
                    Cf[(size_t)(mb + mt * 16 + qd * 4 + r) * 1024 + nb + nt * 16 + l15] = v;
                }
            }
    } else if (mode <= 3) {
        float s1 = (mode == 2) ? 1.f : -1.f;
#pragma unroll
        for (int mt = 0; mt < 4; mt++)
#pragma unroll
            for (int nt = 0; nt < 4; nt++) {
                fx4 s = acc[mt][nt];
#pragma unroll
                for (int r = 0; r < 4; r++) {
                    size_t idx = (size_t)(mb + mt * 16 + qd * 4 + r) * 1024 + nb + nt * 16 + l15;
                    float v = s[r];
                    O1[idx] = f2bf(v * __expf(s1 * cfp[idx]));
                    O2[idx] = f2bf(v * __expf(-s1 * cbp[idx]));
                }
            }
    } else {
        // transpose epilogue -> vvt[(b*1024 + d)][t]
        __syncthreads();
        unsigned short* T = (unsigned short*)smem;   // [128][136]
#pragma unroll
        for (int mt = 0; mt < 4; mt++)
#pragma unroll
            for (int nt = 0; nt < 4; nt++) {
                fx4 s = acc[mt][nt];
                int dl = wn * 64 + nt * 16 + l15;
                int tl = wm * 64 + mt * 16 + qd * 4;
                uint2 pk;
                pk.x = pkbf(s[0], s[1]);
                pk.y = pkbf(s[2], s[3]);
                *(uint2*)(T + dl * 136 + tl) = pk;
            }
        __syncthreads();
        int dl = tid >> 1, hf = tid & 1;
        int bq = m0 >> 10, t0 = m0 & 1023;
#pragma unroll
        for (int i = 0; i < 8; i++) {
            uint4 vv4 = *(const uint4*)(T + dl * 136 + hf * 64 + i * 8);
            *(uint4*)(O1 + (size_t)(bq * 1024 + n0 + dl) * 1024 + t0 + hf * 64 + i * 8) = vv4;
        }
    }
}

__global__ __launch_bounds__(256, 2) void k_gemm4(const unsigned short* __restrict__ xr16,
                                                  const unsigned short* __restrict__ xk16,
                                                  const unsigned short* __restrict__ xv16,
                                                  const unsigned short* __restrict__ xg16,
                                                  const unsigned short* __restrict__ Wrb,
                                                  const unsigned short* __restrict__ Wkb,
                                                  const unsigned short* __restrict__ Wvb,
                                                  const unsigned short* __restrict__ Wgb,
                                                  unsigned short* __restrict__ qf, unsigned short* __restrict__ qb,
                                                  unsigned short* __restrict__ kf, unsigned short* __restrict__ kb,
                                                  unsigned short* __restrict__ vvt,
                                                  float* __restrict__ gg,
                                                  const float* __restrict__ cf, const float* __restrict__ cb) {
    __shared__ __align__(16) char smem[34816];
    int m0 = (blockIdx.x >> 3) * 128, n0 = (blockIdx.x & 7) * 128;
    int y = blockIdx.y;
    if (y == 0)      gemm_body(xr16, Wrb, m0, n0, 2, nullptr, qf, qb, cf, cb, smem);
    else if (y == 1) gemm_body(xk16, Wkb, m0, n0, 3, nullptr, kf, kb, cf, cb, smem);
    else if (y == 2) gemm_body(xv16, Wvb, m0, n0, 4, nullptr, vvt, nullptr, nullptr, nullptr, smem);
    else             gemm_body(xg16, Wgb, m0, n0, 1, gg, nullptr, nullptr, nullptr, nullptr, smem);
}

__global__ __launch_bounds__(256, 2) void k_gemmo(const unsigned short* __restrict__ z16,
                                                  const unsigned short* __restrict__ Wob,
                                                  float* __restrict__ out) {
    __shared__ __align__(16) char smem[34816];
    gemm_body(z16, Wob, (blockIdx.x >> 3) * 128, (blockIdx.x & 7) * 128, 0, out,
              nullptr, nullptr, nullptr, nullptr, smem);
}

// ---------- attention: bidir LION MFMA, no LDS, XCD-swizzled, pair-unrolled ----------
__global__ __launch_bounds__(256, 4) void k_attn(const unsigned short* __restrict__ qf,
                                                 const unsigned short* __restrict__ qb,
                                                 const unsigned short* __restrict__ kf,
                                                 const unsigned short* __restrict__ kb,
                                                 const unsigned short* __restrict__ vvt,
                                                 float* __restrict__ y0,
                                                 float* __restrict__ y1) {
    int tid = threadIdx.x;
    int w = tid >> 6, lane = tid & 63, l15 = lane & 15, qd = lane >> 4;
    int bid = blockIdx.x;            // grid 1024
    // XCD swizzle: all 16 blocks of one (b,h) land on the same XCD (bid % 8)
    int bh = (bid & 7) + ((bid >> 7) << 3);
    int inner = (bid >> 3) & 15;
    int jhalf = inner & 1;
    int ib = inner >> 1;
    int b = bh >> 4, h = bh & 15;
    int i0w = ib * 128 + w * 32;
    int bt0 = b * 1024;
    float* yout = jhalf ? y1 : y0;
    const unsigned short* vb0 = vvt + (size_t)(b * 1024 + h * 64 + l15) * 1024 + qd * 8;
    int nf = ((i0w + 31) >> 6) + 1;   // forward tiles: jt in [0, nf)
    int jb1 = i0w >> 6;               // backward tiles: jt in [jb1, 16)
    int srcA = l15 + ((lane & 16) << 1);   // l15 + 32*(qd&1)
    int srcB = srcA + 16;
    fx4 yacc[4][2];                   // [mt over d][nt over i]
#pragma unroll
    for (int mt = 0; mt < 4; mt++)
#pragma unroll
        for (int nt = 0; nt < 2; nt++)
#pragma unroll
            for (int r = 0; r < 4; r++) yacc[mt][nt][r] = 0.f;

    for (int phase = 0; phase < 2; phase++) {
        const unsigned short* Q = phase ? qb : qf;
        const unsigned short* K = phase ? kb : kf;
        bh8 qfr[2][2];
#pragma unroll
        for (int nt = 0; nt < 2; nt++)
#pragma unroll
            for (int ks = 0; ks < 2; ks++)
                qfr[nt][ks] = *(const bh8*)(Q + (size_t)(bt0 + i0w + nt * 16 + l15) * 1024
                                              + h * 64 + ks * 32 + qd * 8);

        auto qk = [&](int jb, uint2 (&pk)[4][2]) {
            bool needmask = (phase == 0) ? (jb + 63 > i0w) : (i0w + 31 >= jb);
            fx4 sacc[4][2];
#pragma unroll
            for (int mt = 0; mt < 4; mt++)
#pragma unroll
                for (int nt = 0; nt < 2; nt++)
#pragma unroll
                    for (int r = 0; r < 4; r++) sacc[mt][nt][r] = 0.f;
#pragma unroll
            for (int ks = 0; ks < 2; ks++)
#pragma unroll
                for (int mt = 0; mt < 4; mt++) {
                    bh8 kfr = *(const bh8*)(K + (size_t)(bt0 + jb + mt * 16 + l15) * 1024
                                              + h * 64 + ks * 32 + qd * 8);
#pragma unroll
                    for (int nt = 0; nt < 2; nt++)
                        sacc[mt][nt] = __builtin_amdgcn_mfma_f32_16x16x32_bf16(kfr, qfr[nt][ks], sacc[mt][nt], 0, 0, 0);
                }
#pragma unroll
            for (int mt = 0; mt < 4; mt++)
#pragma unroll
                for (int nt = 0; nt < 2; nt++) {
                    fx4 s = sacc[mt][nt];
                    if (needmask) {
                        int ii = i0w + nt * 16 + l15;
                        int jj0 = jb + mt * 16 + qd * 4;
#pragma unroll
                        for (int r = 0; r < 4; r++) {
                            bool keep = (phase == 0) ? (ii >= jj0 + r) : (ii < jj0 + r);
                            if (!keep) s[r] = 0.f;
                        }
                    }
                    pk[mt][nt].x = pkbf(s[0], s[1]);
                    pk[mt][nt].y = pkbf(s[2], s[3]);
                }
        };
        auto sv = [&](int jb, uint2 (&pk)[4][2]) {
#pragma unroll
            for (int ks2 = 0; ks2 < 2; ks2++) {
                bh8 av[4];
#pragma unroll
                for (int mt = 0; mt < 4; mt++)
                    av[mt] = *(const bh8*)(vb0 + (size_t)(mt * 16) * 1024 + jb + ks2 * 32);
#pragma unroll
                for (int nt = 0; nt < 2; nt++) {
                    int lox  = __shfl((int)pk[2 * ks2][nt].x,     srcA);
                    int hix  = __shfl((int)pk[2 * ks2 + 1][nt].x, srcA);
                    int loy  = __shfl((int)pk[2 * ks2][nt].y,     srcA);
                    int hiy  = __shfl((int)pk[2 * ks2 + 1][nt].y, srcA);
                    int lox2 = __shfl((int)pk[2 * ks2][nt].x,     srcB);
                    int hix2 = __shfl((int)pk[2 * ks2 + 1][nt].x, srcB);
                    int loy2 = __shfl((int)pk[2 * ks2][nt].y,     srcB);
                    int hiy2 = __shfl((int)pk[2 * ks2 + 1][nt].y, srcB);
                    union { int4 i; bh8 h; } cv;
                    cv.i.x = (qd & 2) ? hix  : lox;
                    cv.i.y = (qd & 2) ? hiy  : loy;
                    cv.i.z = (qd & 2) ? hix2 : lox2;
                    cv.i.w = (qd & 2) ? hiy2 : loy2;
#pragma unroll
                    for (int mt = 0; mt < 4; mt++)
                        yacc[mt][nt] = __builtin_amdgcn_mfma_f32_16x16x32_bf16(av[mt], cv.h, yacc[mt][nt], 0, 0, 0);
                }
            }
        };

        int jt   = (phase == 0) ? jhalf : jb1 + ((jhalf + nf) & 1);
        int jend = (phase == 0) ? nf - 1 : 15;
        // pair-unrolled: two independent tile chains in flight
        for (; jt + 2 <= jend; jt += 4) {
            uint2 pkA[4][2], pkB[4][2];
            qk(jt * 64, pkA);
            qk(jt * 64 + 128, pkB);
            sv(jt * 64, pkA);
            sv(jt * 64 + 128, pkB);
        }
        if (jt <= jend) {
            uint2 pkA[4][2];
            qk(jt * 64, pkA);
            sv(jt * 64, pkA);
        }
    }
    // store y^T C-frags: i = col, d = row -> float4 along d
#pragma unroll
    for (int mt = 0; mt < 4; mt++)
#pragma unroll
        for (int nt = 0; nt < 2; nt++) {
            fx4 s = yacc[mt][nt];
            float4 o; o.x = s[0]; o.y = s[1]; o.z = s[2]; o.w = s[3];
            *(float4*)&yout[(size_t)(bt0 + i0w + nt * 16 + l15) * 1024 + h * 64 + mt * 16 + qd * 4] = o;
        }
}

// ---------- groupnorm * g -> bf16 z (sums the two attention partials) ----------
__global__ __launch_bounds__(256) void k_gn(const float* __restrict__ y0,
                                            const float* __restrict__ y1,
                                            const float* __restrict__ g,
                                            const float* __restrict__ lnw,
                                            const float* __restrict__ lnb,
                                            unsigned short* __restrict__ z16) {
    int tid = threadIdx.x;
    int lane = tid & 63;
    int wv = tid >> 6;
    int group = blockIdx.x * 4 + wv;     // grid 16384
    int tok = group >> 4, h = group & 15;
    int d = h * 64 + lane;
    size_t idx = (size_t)tok * 1024 + d;
    float val = y0[idx] + y1[idx];
    float s = val, s2 = val * val;
#pragma unroll
    for (int off = 32; off > 0; off >>= 1) {
        s  += __shfl_xor(s, off, 64);
        s2 += __shfl_xor(s2, off, 64);
    }
    float mu = s * (1.f / 64.f);
    float var = s2 * (1.f / 64.f) - mu * mu;
    float inv = rsqrtf(var + 6.4e-4f);
    float yn = (val - mu) * inv * lnw[d] + lnb[d];
    z16[idx] = f2bf(yn * g[idx]);
}

extern "C" void kernel_launch(void* const* d_in, const int* in_sizes, int n_in,
                              void* d_out, int out_size, void* d_ws, size_t ws_size,
                              hipStream_t stream) {
    const float* x     = (const float*)d_in[0];
    const float* maa_x = (const float*)d_in[1];
    const float* maa_w = (const float*)d_in[2];
    const float* maa_k = (const float*)d_in[3];
    const float* maa_v = (const float*)d_in[4];
    const float* maa_r = (const float*)d_in[5];
    const float* maa_g = (const float*)d_in[6];
    const float* w1    = (const float*)d_in[7];
    const float* w2    = (const float*)d_in[8];
    const float* tdec  = (const float*)d_in[9];
    const float* dw1   = (const float*)d_in[10];
    const float* dw2   = (const float*)d_in[11];
    const float* W_r   = (const float*)d_in[12];
    const float* W_k   = (const float*)d_in[13];
    const float* W_v   = (const float*)d_in[14];
    const float* W_g   = (const float*)d_in[15];
    const float* W_o   = (const float*)d_in[16];
    const float* lnw   = (const float*)d_in[17];
    const float* lnb   = (const float*)d_in[18];

    float* ws = (float*)d_ws;
    size_t o = 0;
    float* dech   = ws + o; o += 262144;
    float* segsum = ws + o; o += 131072;
    float* ew     = ws + o; o += 4194304;
    float* cf     = ws + o; o += 4194304;
    float* cb     = ws + o; o += 4194304;
    float* gg     = ws + o; o += 4194304;
    unsigned short* us = (unsigned short*)(ws + o);
    size_t u = 0;
    unsigned short* xw16 = us + u; u += 4194304;
    unsigned short* xr16 = us + u; u += 4194304;   // also z16 after gemm4
    unsigned short* xk16 = us + u; u += 4194304;
    unsigned short* xv16 = us + u; u += 4194304;
    unsigned short* xg16 = us + u; u += 4194304;
    unsigned short* qf   = us + u; u += 4194304;
    unsigned short* qb   = us + u; u += 4194304;
    unsigned short* kf   = us + u; u += 4194304;
    unsigned short* kb   = us + u; u += 4194304;
    unsigned short* vvt  = us + u; u += 4194304;
    unsigned short* Wrb  = us + u; u += 1048576;
    unsigned short* Wkb  = us + u; u += 1048576;
    unsigned short* Wvb  = us + u; u += 1048576;
    unsigned short* Wgb  = us + u; u += 1048576;
    unsigned short* Wob  = us + u; u += 1048576;
    unsigned short* w1T  = us + u; u += 163840;
    unsigned short* dw1T = us + u; u += 65536;
    unsigned short* xxx16 = us + u; u += 655360;
    unsigned short* w2T16 = us + u; u += 163840;
    float* yb0 = cf;               // attention partials reuse cf/cb (dead after gemm4)
    float* yb1 = cb;
    unsigned short* z16 = xr16;    // dead after gemm4

    k_prep<<<dim3(640, 7), 256, 0, stream>>>(W_r, W_k, W_v, W_g, W_o, w1, dw1, w2,
                                             Wrb, Wkb, Wvb, Wgb, Wob, w1T, dw1T, w2T16);
    k_xxx2<<<256, 64, 0, stream>>>(x, maa_x, w1T, xxx16);
    k_mmix<<<dim3(16, 32), 256, 0, stream>>>(x, xxx16, w2T16, maa_w, maa_k, maa_v, maa_r, maa_g,
                                             xw16, xk16, xv16, xr16, xg16);
    k_dec1m<<<256, 64, 0, stream>>>(xw16, dw1T, dech);
    k_dec2<<<512, 256, 0, stream>>>(dech, dw2, tdec, ew);
    k_scan1<<<2048, 64, 0, stream>>>(ew, segsum);
    k_scan3<<<2048, 64, 0, stream>>>(ew, segsum, cf, cb);
    k_gemm4<<<dim3(256, 4), 256, 0, stream>>>(xr16, xk16, xv16, xg16, Wrb, Wkb, Wvb, Wgb,
                                              qf, qb, kf, kb, vvt, gg, cf, cb);
    k_attn<<<1024, 256, 0, stream>>>(qf, qb, kf, kb, vvt, yb0, yb1);
    k_gn<<<16384, 256, 0, stream>>>(yb0, yb1, gg, lnw, lnb, z16);
    k_gemmo<<<256, 256, 0, stream>>>(z16, Wob, (float*)d_out);
}

// Round 8
// 394.680 us; speedup vs baseline: 1.1616x; 1.1616x over previous
//
#include <hip/hip_runtime.h>
#include <math.h>

#define NB 4
#define TT 1024
#define DD 1024
#define NTOK 4096
#define ND (NTOK*DD)

typedef __attribute__((ext_vector_type(8))) short bh8;
typedef __attribute__((ext_vector_type(4))) float fx4;

__device__ __forceinline__ unsigned short f2bf(float f) {
    unsigned int b = __float_as_uint(f);
    b += 0x7fffu + ((b >> 16) & 1u);
    return (unsigned short)(b >> 16);
}

// pack two fp32 -> packed bf16 (RNE); HW v_cvt_pk_bf16_f32 when available
__device__ __forceinline__ unsigned pkbf(float a, float b) {
#if __has_builtin(__builtin_amdgcn_cvt_pk_bf16_f32)
    auto r = __builtin_amdgcn_cvt_pk_bf16_f32(a, b);
    unsigned u;
    __builtin_memcpy(&u, &r, 4);
    return u;
#else
    return ((unsigned)f2bf(b) << 16) | f2bf(a);
#endif
}

// async global->LDS, 16B per lane, LDS dst = wave-uniform base + lane*16
#define GLD16(gp, lp) __builtin_amdgcn_global_load_lds( \
    (__attribute__((address_space(1))) void*)(gp), \
    (__attribute__((address_space(3))) void*)(lp), 16, 0, 0)

// ---------- fused preprocessing: 5x wconv, w1T, dw1T, w2T ----------
__global__ __launch_bounds__(256) void k_prep(const float* __restrict__ W_r, const float* __restrict__ W_k,
                                              const float* __restrict__ W_v, const float* __restrict__ W_g,
                                              const float* __restrict__ W_o,
                                              const float* __restrict__ w1, const float* __restrict__ dw1,
                                              const float* __restrict__ w2,
                                              unsigned short* __restrict__ Wrb, unsigned short* __restrict__ Wkb,
                                              unsigned short* __restrict__ Wvb, unsigned short* __restrict__ Wgb,
                                              unsigned short* __restrict__ Wob,
                                              unsigned short* __restrict__ w1T, unsigned short* __restrict__ dw1T,
                                              unsigned short* __restrict__ w2T16) {
    int y = blockIdx.y, bx = blockIdx.x, tid = threadIdx.x;   // grid (640, 7)
    if (y < 5) {
        if (bx >= 512) return;
        const float* s = (y == 0) ? W_r : (y == 1) ? W_k : (y == 2) ? W_v : (y == 3) ? W_g : W_o;
        unsigned short* d = (y == 0) ? Wrb : (y == 1) ? Wkb : (y == 2) ? Wvb : (y == 3) ? Wgb : Wob;
        int i = (bx * 256 + tid) * 8;
        float4 a = *(const float4*)(s + i);
        float4 b = *(const float4*)(s + i + 4);
        uint4 o;
        o.x = pkbf(a.x, a.y);
        o.y = pkbf(a.z, a.w);
        o.z = pkbf(b.x, b.y);
        o.w = pkbf(b.z, b.w);
        *(uint4*)(d + i) = o;
    } else if (y == 5) {
        int o = bx * 256 + tid;          // 163840 total
        int r = o & 1023, c = o >> 10;
        w1T[o] = f2bf(w1[r * 160 + c]);
    } else {
        if (bx < 256) {
            int o = bx * 256 + tid;      // 65536 total
            int r = o & 1023, c = o >> 10;
            dw1T[o] = f2bf(dw1[r * 64 + c]);
        } else if (bx < 276) {
            int wi = bx - 256;
            int f = wi >> 2;
            int d = (wi & 3) * 256 + tid;
#pragma unroll 8
            for (int m = 0; m < 32; m++)
                w2T16[(size_t)(f * 1024 + d) * 32 + m] = f2bf(w2[(size_t)(f * 32 + m) * 1024 + d]);
        }
    }
}

// ---------- k1: xmix16 = bf16(x + dxprev * maa_x) ----------
__global__ __launch_bounds__(256) void k_mixx(const float* __restrict__ x,
                                              const float* __restrict__ maa_x,
                                              unsigned short* __restrict__ xmix16) {
    int base = (blockIdx.x * 256 + threadIdx.x) * 4;   // grid 4096
    int t = (base >> 10) & 1023;
    int d = base & 1023;
    float4 xv = *(const float4*)(x + base);
    float4 xm = (t > 0)    ? *(const float4*)(x + base - 1024) : make_float4(0, 0, 0, 0);
    float4 xp = (t < 1023) ? *(const float4*)(x + base + 1024) : make_float4(0, 0, 0, 0);
    float4 ma = *(const float4*)(maa_x + d);
    uint2 o;
    float a0 = xv.x + (0.5f * (xm.x + xp.x) - xv.x) * ma.x;
    float a1 = xv.y + (0.5f * (xm.y + xp.y) - xv.y) * ma.y;
    float a2 = xv.z + (0.5f * (xm.z + xp.z) - xv.z) * ma.z;
    float a3 = xv.w + (0.5f * (xm.w + xp.w) - xv.w) * ma.w;
    o.x = pkbf(a0, a1);
    o.y = pkbf(a2, a3);
    *(uint2*)(xmix16 + base) = o;
}

// ---------- k2: xxx16 = bf16(tanh(xmix @ w1)) via MFMA, 1-wave blocks ----------
__global__ __launch_bounds__(64) void k_xxx2(const unsigned short* __restrict__ xmix16,
                                             const unsigned short* __restrict__ w1T,
                                             unsigned short* __restrict__ xxx16) {
    int lane = threadIdx.x;
    int l15 = lane & 15, qd = lane >> 4;
    int m0 = blockIdx.x * 16;    // grid 256
    fx4 acc[10];
#pragma unroll
    for (int nt = 0; nt < 10; nt++)
#pragma unroll
        for (int r = 0; r < 4; r++) acc[nt][r] = 0.f;
#pragma unroll 2
    for (int kb = 0; kb < 1024; kb += 32) {
        bh8 af = *(const bh8*)(xmix16 + (size_t)(m0 + l15) * 1024 + kb + qd * 8);
#pragma unroll
        for (int nt = 0; nt < 10; nt++) {
            bh8 bf = *(const bh8*)(w1T + (size_t)(nt * 16 + l15) * 1024 + kb + qd * 8);
            acc[nt] = __builtin_amdgcn_mfma_f32_16x16x32_bf16(af, bf, acc[nt], 0, 0, 0);
        }
    }
#pragma unroll
    for (int nt = 0; nt < 10; nt++)
#pragma unroll
        for (int r = 0; r < 4; r++)
            xxx16[(size_t)(m0 + qd * 4 + r) * 160 + nt * 16 + l15] = f2bf(tanhf(acc[nt][r]));
}

// ---------- k3: fused mm-einsum (MFMA, K=32) + five mixes, no LDS ----------
__global__ __launch_bounds__(256, 2) void k_mmix(const float* __restrict__ x,
                                                 const unsigned short* __restrict__ xxx16,
                                                 const unsigned short* __restrict__ w2T16,
                                                 const float* __restrict__ maa_w,
                                                 const float* __restrict__ maa_k,
                                                 const float* __restrict__ maa_v,
                                                 const float* __restrict__ maa_r,
                                                 const float* __restrict__ maa_g,
                                                 unsigned short* __restrict__ xw16,
                                                 unsigned short* __restrict__ xk16,
                                                 unsigned short* __restrict__ xv16,
                                                 unsigned short* __restrict__ xr16,
                                                 unsigned short* __restrict__ xg16) {
    int tid = threadIdx.x;
    int w = tid >> 6, lane = tid & 63, l15 = lane & 15, qd = lane >> 4;
    int n0 = blockIdx.x * 64;               // grid (16, 32)
    int m0w = blockIdx.y * 128 + w * 32;
    const float* maap[5] = {maa_w, maa_k, maa_v, maa_r, maa_g};
    unsigned short* outp[5] = {xw16, xk16, xv16, xr16, xg16};
    float xin[8][4], dxv[8][4];
#pragma unroll
    for (int mi = 0; mi < 2; mi++)
#pragma unroll
        for (int r = 0; r < 4; r++) {
            int tok = m0w + mi * 16 + qd * 4 + r;
            int t = tok & 1023;
#pragma unroll
            for (int ni = 0; ni < 4; ni++) {
                int d = n0 + ni * 16 + l15;
                size_t idx = (size_t)tok * 1024 + d;
                float xv = x[idx];
                float xm1 = (t > 0)    ? x[idx - 1024] : 0.f;
                float xp1 = (t < 1023) ? x[idx + 1024] : 0.f;
                xin[mi * 4 + r][ni] = xv;
                dxv[mi * 4 + r][ni] = 0.5f * (xm1 + xp1) - xv;
            }
        }
#pragma unroll
    for (int f = 0; f < 5; f++) {
        bh8 af[2], bf[4];
#pragma unroll
        for (int mi = 0; mi < 2; mi++)
            af[mi] = *(const bh8*)(xxx16 + (size_t)(m0w + mi * 16 + l15) * 160 + f * 32 + qd * 8);
#pragma unroll
        for (int ni = 0; ni < 4; ni++)
            bf[ni] = *(const bh8*)(w2T16 + (size_t)(f * 1024 + n0 + ni * 16 + l15) * 32 + qd * 8);
        fx4 acc[2][4];
#pragma unroll
        for (int mi = 0; mi < 2; mi++)
#pragma unroll
            for (int ni = 0; ni < 4; ni++) {
#pragma unroll
                for (int r = 0; r < 4; r++) acc[mi][ni][r] = 0.f;
                acc[mi][ni] = __builtin_amdgcn_mfma_f32_16x16x32_bf16(af[mi], bf[ni], acc[mi][ni], 0, 0, 0);
            }
        const float* maa = maap[f];
        unsigned short* op = outp[f];
#pragma unroll
        for (int ni = 0; ni < 4; ni++) {
            float mv = maa[n0 + ni * 16 + l15];
#pragma unroll
            for (int mi = 0; mi < 2; mi++)
#pragma unroll
                for (int r = 0; r < 4; r++) {
                    float o = xin[mi * 4 + r][ni] + dxv[mi * 4 + r][ni] * (mv + acc[mi][ni][r]);
                    op[(size_t)(m0w + mi * 16 + qd * 4 + r) * 1024 + n0 + ni * 16 + l15] = f2bf(o);
                }
        }
    }
}

// ---------- decay GEMM1 via MFMA: dech = tanh(xw @ dw1), 1-wave blocks ----------
__global__ __launch_bounds__(64) void k_dec1m(const unsigned short* __restrict__ xw16,
                                              const unsigned short* __restrict__ dw1T,
                                              float* __restrict__ dech) {
    int lane = threadIdx.x;
    int l15 = lane & 15, qd = lane >> 4;
    int m0 = blockIdx.x * 16;    // grid 256
    fx4 acc[4];
#pragma unroll
    for (int nt = 0; nt < 4; nt++)
#pragma unroll
        for (int r = 0; r < 4; r++) acc[nt][r] = 0.f;
#pragma unroll 2
    for (int kb = 0; kb < 1024; kb += 32) {
        bh8 af = *(const bh8*)(xw16 + (size_t)(m0 + l15) * 1024 + kb + qd * 8);
#pragma unroll
        for (int nt = 0; nt < 4; nt++) {
            bh8 bf = *(const bh8*)(dw1T + (size_t)(nt * 16 + l15) * 1024 + kb + qd * 8);
            acc[nt] = __builtin_amdgcn_mfma_f32_16x16x32_bf16(af, bf, acc[nt], 0, 0, 0);
        }
    }
#pragma unroll
    for (int nt = 0; nt < 4; nt++)
#pragma unroll
        for (int r = 0; r < 4; r++)
            dech[(size_t)(m0 + qd * 4 + r) * 64 + nt * 16 + l15] = tanhf(acc[nt][r]);
}

// ---------- decay GEMM2: ew = -exp(time_decay + dech @ dw2) ----------
__global__ __launch_bounds__(256) void k_dec2(const float* __restrict__ dech,
                                              const float* __restrict__ dw2,
                                              const float* __restrict__ tdec,
                                              float* __restrict__ ew) {
    __shared__ float hl[8][64];
    int tid = threadIdx.x;
    int tok0 = blockIdx.x * 8;     // grid 512
    {
        int l = tid;        hl[l >> 6][l & 63] = dech[tok0 * 64 + l];
        l = tid + 256;      hl[l >> 6][l & 63] = dech[tok0 * 64 + l];
    }
    __syncthreads();
#pragma unroll 1
    for (int c = 0; c < 4; c++) {
        int d = c * 256 + tid;
        float acc[8] = {};
#pragma unroll 8
        for (int j = 0; j < 64; j++) {
            float wv = dw2[j * 1024 + d];
#pragma unroll
            for (int g = 0; g < 8; g++) acc[g] = fmaf(hl[g][j], wv, acc[g]);
        }
        float td = tdec[d];
#pragma unroll
        for (int g = 0; g < 8; g++) ew[(tok0 + g) * 1024 + d] = -expf(td + acc[g]);
    }
}

// ---------- scan stage 1: per-segment sums (seg = 32) ----------
__global__ __launch_bounds__(64) void k_scan1(const float* __restrict__ ew, float* __restrict__ segsum) {
    int bx = blockIdx.x;            // grid 2048 = 4b x 32seg x 16dch
    int b = bx >> 9, seg = (bx >> 4) & 31, dch = bx & 15;
    int d = dch * 64 + threadIdx.x;
    size_t base = ((size_t)(b * 1024 + seg * 32)) * 1024 + d;
    float s = 0.f;
#pragma unroll 8
    for (int t = 0; t < 32; t++) s += ew[base + (size_t)t * 1024];
    segsum[(b * 32 + seg) * 1024 + d] = s;
}

// ---------- scan stage 2+3 fused: local prefix of segsums + emit clipped cf/cb ----------
__global__ __launch_bounds__(64) void k_scan3(const float* __restrict__ ew, const float* __restrict__ segsum,
                                              float* __restrict__ cf, float* __restrict__ cb) {
    int bx = blockIdx.x;            // grid 2048
    int b = bx >> 9, seg = (bx >> 4) & 31, dch = bx & 15;
    int d = dch * 64 + threadIdx.x;
    float run = 0.f, pre = 0.f, off16 = 0.f;
#pragma unroll
    for (int s = 0; s < 32; s++) {
        float tv = segsum[(b * 32 + s) * 1024 + d];
        if (s == seg) pre = run;
        if (s == 16) off16 = run;
        run += tv;
    }
    float e512 = ew[((size_t)(b * 1024 + 512)) * 1024 + d];
    float sb = off16;           // cs[511]
    float sf = off16 + e512;    // cs[512]
    float cum = pre;
    size_t base = ((size_t)(b * 1024 + seg * 32)) * 1024 + d;
#pragma unroll 4
    for (int t = 0; t < 32; t++) {
        float prev = cum;
        cum += ew[base + (size_t)t * 1024];
        cf[base + (size_t)t * 1024] = fminf(fmaxf(cum - sf, -60.f), 60.f);
        cb[base + (size_t)t * 1024] = fminf(fmaxf(prev - sb, -60.f), 60.f);
    }
}

// ---------- bf16 MFMA GEMM core: C[4096][1024] = A @ W^T, async LDS staging ----------
// modes: 0 fp32 out, 1 silu fp32, 2 q-exp (O1=qf,O2=qb), 3 k-exp (O1=kf,O2=kb), 4 v-transpose (O1=vvt)
__device__ __forceinline__ void gemm_body(const unsigned short* __restrict__ A,
                                          const unsigned short* __restrict__ W,
                                          int m0, int n0, int mode,
                                          float* __restrict__ Cf,
                                          unsigned short* __restrict__ O1,
                                          unsigned short* __restrict__ O2,
                                          const float* __restrict__ cfp,
                                          const float* __restrict__ cbp,
                                          char* smem) {
    int tid = threadIdx.x;
    int w = tid >> 6, lane = tid & 63, l15 = lane & 15, qd = lane >> 4;
    int wm = w >> 1, wn = w & 1;
    fx4 acc[4][4];
#pragma unroll
    for (int mt = 0; mt < 4; mt++)
#pragma unroll
        for (int nt = 0; nt < 4; nt++)
#pragma unroll
            for (int r = 0; r < 4; r++) acc[mt][nt][r] = 0.f;
    unsigned short* sA = (unsigned short*)smem;            // [128][32]
    unsigned short* sB = (unsigned short*)(smem + 8192);   // [128][32]
    int rowA = tid >> 2, cA = tid & 3;
    for (int kb = 0; kb < 1024; kb += 32) {
        __syncthreads();
        GLD16(A + (size_t)(m0 + rowA) * 1024 + kb + cA * 8,      sA + w * 512);
        GLD16(A + (size_t)(m0 + 64 + rowA) * 1024 + kb + cA * 8, sA + 2048 + w * 512);
        GLD16(W + (size_t)(n0 + rowA) * 1024 + kb + cA * 8,      sB + w * 512);
        GLD16(W + (size_t)(n0 + 64 + rowA) * 1024 + kb + cA * 8, sB + 2048 + w * 512);
        __syncthreads();
        bh8 af[4], bfr[4];
#pragma unroll
        for (int mt = 0; mt < 4; mt++)
            af[mt] = *(const bh8*)(sA + (wm * 64 + mt * 16 + l15) * 32 + qd * 8);
#pragma unroll
        for (int nt = 0; nt < 4; nt++)
            bfr[nt] = *(const bh8*)(sB + (wn * 64 + nt * 16 + l15) * 32 + qd * 8);
#pragma unroll
        for (int mt = 0; mt < 4; mt++)
#pragma unroll
            for (int nt = 0; nt < 4; nt++)
                acc[mt][nt] = __builtin_amdgcn_mfma_f32_16x16x32_bf16(af[mt], bfr[nt], acc[mt][nt], 0, 0, 0);
    }
    int mb = m0 + wm * 64, nb = n0 + wn * 64;
    if (mode <= 1) {
#pragma unroll
        for (int mt = 0; mt < 4; mt++)
#pragma unroll
            for (int nt = 0; nt < 4; nt++) {
                fx4 s = acc[mt][nt];
#pragma unroll
                for (int r = 0; r < 4; r++) {
                    float v = s[r];
                    if (mode == 1) v = v / (1.f + __expf(-v));
                    Cf[(size_t)(mb + mt * 16 + qd * 4 + r) * 1024 + nb + nt * 16 + l15] = v;
                }
            }
    } else if (mode <= 3) {
        float s1 = (mode == 2) ? 1.f : -1.f;
#pragma unroll
        for (int mt = 0; mt < 4; mt++)
#pragma unroll
            for (int nt = 0; nt < 4; nt++) {
                fx4 s = acc[mt][nt];
#pragma unroll
                for (int r = 0; r < 4; r++) {
                    size_t idx = (size_t)(mb + mt * 16 + qd * 4 + r) * 1024 + nb + nt * 16 + l15;
                    float v = s[r];
                    O1[idx] = f2bf(v * __expf(s1 * cfp[idx]));
                    O2[idx] = f2bf(v * __expf(-s1 * cbp[idx]));
                }
            }
    } else {
        // transpose epilogue -> vvt[(b*1024 + d)][t]
        __syncthreads();
        unsigned short* T = (unsigned short*)smem;   // [128][136]
#pragma unroll
        for (int mt = 0; mt < 4; mt++)
#pragma unroll
            for (int nt = 0; nt < 4; nt++) {
                fx4 s = acc[mt][nt];
                int dl = wn * 64 + nt * 16 + l15;
                int tl = wm * 64 + mt * 16 + qd * 4;
                uint2 pk;
                pk.x = pkbf(s[0], s[1]);
                pk.y = pkbf(s[2], s[3]);
                *(uint2*)(T + dl * 136 + tl) = pk;
            }
        __syncthreads();
        int dl = tid >> 1, hf = tid & 1;
        int bq = m0 >> 10, t0 = m0 & 1023;
#pragma unroll
        for (int i = 0; i < 8; i++) {
            uint4 vv4 = *(const uint4*)(T + dl * 136 + hf * 64 + i * 8);
            *(uint4*)(O1 + (size_t)(bq * 1024 + n0 + dl) * 1024 + t0 + hf * 64 + i * 8) = vv4;
        }
    }
}

__global__ __launch_bounds__(256, 2) void k_gemm4(const unsigned short* __restrict__ xr16,
                                                  const unsigned short* __restrict__ xk16,
                                                  const unsigned short* __restrict__ xv16,
                                                  const unsigned short* __restrict__ xg16,
                                                  const unsigned short* __restrict__ Wrb,
                                                  const unsigned short* __restrict__ Wkb,
                                                  const unsigned short* __restrict__ Wvb,
                                                  const unsigned short* __restrict__ Wgb,
                                                  unsigned short* __restrict__ qf, unsigned short* __restrict__ qb,
                                                  unsigned short* __restrict__ kf, unsigned short* __restrict__ kb,
                                                  unsigned short* __restrict__ vvt,
                                                  float* __restrict__ gg,
                                                  const float* __restrict__ cf, const float* __restrict__ cb) {
    __shared__ __align__(16) char smem[34816];
    int m0 = (blockIdx.x >> 3) * 128, n0 = (blockIdx.x & 7) * 128;
    int y = blockIdx.y;
    if (y == 0)      gemm_body(xr16, Wrb, m0, n0, 2, nullptr, qf, qb, cf, cb, smem);
    else if (y == 1) gemm_body(xk16, Wkb, m0, n0, 3, nullptr, kf, kb, cf, cb, smem);
    else if (y == 2) gemm_body(xv16, Wvb, m0, n0, 4, nullptr, vvt, nullptr, nullptr, nullptr, smem);
    else             gemm_body(xg16, Wgb, m0, n0, 1, gg, nullptr, nullptr, nullptr, nullptr, smem);
}

__global__ __launch_bounds__(256, 2) void k_gemmo(const unsigned short* __restrict__ z16,
                                                  const unsigned short* __restrict__ Wob,
                                                  float* __restrict__ out) {
    __shared__ __align__(16) char smem[34816];
    gemm_body(z16, Wob, (blockIdx.x >> 3) * 128, (blockIdx.x & 7) * 128, 0, out,
              nullptr, nullptr, nullptr, nullptr, smem);
}

// ---------- attention: bidir LION MFMA, no LDS, XCD swizzle, K-prefetch, straight-line ----------
__global__ __launch_bounds__(256, 2) void k_attn(const unsigned short* __restrict__ qf,
                                                 const unsigned short* __restrict__ qb,
                                                 const unsigned short* __restrict__ kf,
                                                 const unsigned short* __restrict__ kb,
                                                 const unsigned short* __restrict__ vvt,
                                                 float* __restrict__ y0,
                                                 float* __restrict__ y1) {
    int tid = threadIdx.x;
    int w = tid >> 6, lane = tid & 63, l15 = lane & 15, qd = lane >> 4;
    int bid = blockIdx.x;            // grid 1024
    // XCD swizzle: all 16 blocks of one (b,h) land on the same XCD (bid % 8)
    int bh = (bid & 7) + ((bid >> 7) << 3);
    int inner = (bid >> 3) & 15;
    int jhalf = inner & 1;
    int ib = inner >> 1;
    int b = bh >> 4, h = bh & 15;
    int i0w = ib * 128 + w * 32;
    int bt0 = b * 1024;
    float* yout = jhalf ? y1 : y0;
    const unsigned short* vb0 = vvt + (size_t)(b * 1024 + h * 64 + l15) * 1024 + qd * 8;
    int nf = ((i0w + 31) >> 6) + 1;   // forward tiles: jt in [0, nf)
    int jb1 = i0w >> 6;               // backward tiles: jt in [jb1, 16)
    int srcA = l15 + ((lane & 16) << 1);   // l15 + 32*(qd&1)
    int srcB = srcA + 16;
    fx4 yacc[4][2];                   // [mt over d][nt over i]
#pragma unroll
    for (int mt = 0; mt < 4; mt++)
#pragma unroll
        for (int nt = 0; nt < 2; nt++)
#pragma unroll
            for (int r = 0; r < 4; r++) yacc[mt][nt][r] = 0.f;

    for (int phase = 0; phase < 2; phase++) {
        const unsigned short* Q = phase ? qb : qf;
        const unsigned short* K = phase ? kb : kf;
        bh8 qfr[2][2];
#pragma unroll
        for (int nt = 0; nt < 2; nt++)
#pragma unroll
            for (int ks = 0; ks < 2; ks++)
                qfr[nt][ks] = *(const bh8*)(Q + (size_t)(bt0 + i0w + nt * 16 + l15) * 1024
                                              + h * 64 + ks * 32 + qd * 8);
        int jt   = (phase == 0) ? jhalf : jb1 + ((jhalf + nf) & 1);
        int jend = (phase == 0) ? nf - 1 : 15;
        if (jt > jend) continue;
        // preload K frags for first tile
        bh8 kc[8];
        {
            int jb = jt * 64;
#pragma unroll
            for (int ks = 0; ks < 2; ks++)
#pragma unroll
                for (int mt = 0; mt < 4; mt++)
                    kc[ks * 4 + mt] = *(const bh8*)(K + (size_t)(bt0 + jb + mt * 16 + l15) * 1024
                                                      + h * 64 + ks * 32 + qd * 8);
        }
        for (; jt <= jend; jt += 2) {
            int jb = jt * 64;
            int jn = jt + 2;
            // prefetch next tile's K frags (full pass of slack)
            bh8 kn[8];
            if (jn <= jend) {
                int jbn = jn * 64;
#pragma unroll
                for (int ks = 0; ks < 2; ks++)
#pragma unroll
                    for (int mt = 0; mt < 4; mt++)
                        kn[ks * 4 + mt] = *(const bh8*)(K + (size_t)(bt0 + jbn + mt * 16 + l15) * 1024
                                                          + h * 64 + ks * 32 + qd * 8);
            } else {
#pragma unroll
                for (int i = 0; i < 8; i++) kn[i] = kc[i];
            }
            // QK: S^T tile (64j x 32i), A = K rows(j), B = Q rows(i)
            fx4 sacc[4][2];
#pragma unroll
            for (int mt = 0; mt < 4; mt++)
#pragma unroll
                for (int nt = 0; nt < 2; nt++)
#pragma unroll
                    for (int r = 0; r < 4; r++) sacc[mt][nt][r] = 0.f;
#pragma unroll
            for (int ks = 0; ks < 2; ks++)
#pragma unroll
                for (int mt = 0; mt < 4; mt++)
#pragma unroll
                    for (int nt = 0; nt < 2; nt++)
                        sacc[mt][nt] = __builtin_amdgcn_mfma_f32_16x16x32_bf16(kc[ks * 4 + mt], qfr[nt][ks], sacc[mt][nt], 0, 0, 0);
            // V loads for current tile — issued early, consumed after shfl
            bh8 vc[8];
#pragma unroll
            for (int ks2 = 0; ks2 < 2; ks2++)
#pragma unroll
                for (int mt = 0; mt < 4; mt++)
                    vc[ks2 * 4 + mt] = *(const bh8*)(vb0 + (size_t)(mt * 16) * 1024 + jb + ks2 * 32);
            // mask + pack bf16
            bool needmask = (phase == 0) ? (jb + 63 > i0w) : (i0w + 31 >= jb);
            uint2 pk[4][2];
#pragma unroll
            for (int mt = 0; mt < 4; mt++)
#pragma unroll
                for (int nt = 0; nt < 2; nt++) {
                    fx4 s = sacc[mt][nt];
                    if (needmask) {
                        int ii = i0w + nt * 16 + l15;
                        int jj0 = jb + mt * 16 + qd * 4;
#pragma unroll
                        for (int r = 0; r < 4; r++) {
                            bool keep = (phase == 0) ? (ii >= jj0 + r) : (ii < jj0 + r);
                            if (!keep) s[r] = 0.f;
                        }
                    }
                    pk[mt][nt].x = pkbf(s[0], s[1]);
                    pk[mt][nt].y = pkbf(s[2], s[3]);
                }
            // y^T += V^T * S^T : B = S^T frag via shfl redistribution
#pragma unroll
            for (int ks2 = 0; ks2 < 2; ks2++) {
#pragma unroll
                for (int nt = 0; nt < 2; nt++) {
                    int lox  = __shfl((int)pk[2 * ks2][nt].x,     srcA);
                    int hix  = __shfl((int)pk[2 * ks2 + 1][nt].x, srcA);
                    int loy  = __shfl((int)pk[2 * ks2][nt].y,     srcA);
                    int hiy  = __shfl((int)pk[2 * ks2 + 1][nt].y, srcA);
                    int lox2 = __shfl((int)pk[2 * ks2][nt].x,     srcB);
                    int hix2 = __shfl((int)pk[2 * ks2 + 1][nt].x, srcB);
                    int loy2 = __shfl((int)pk[2 * ks2][nt].y,     srcB);
                    int hiy2 = __shfl((int)pk[2 * ks2 + 1][nt].y, srcB);
                    union { int4 i; bh8 h; } cv;
                    cv.i.x = (qd & 2) ? hix  : lox;
                    cv.i.y = (qd & 2) ? hiy  : loy;
                    cv.i.z = (qd & 2) ? hix2 : lox2;
                    cv.i.w = (qd & 2) ? hiy2 : loy2;
#pragma unroll
                    for (int mt = 0; mt < 4; mt++)
                        yacc[mt][nt] = __builtin_amdgcn_mfma_f32_16x16x32_bf16(vc[ks2 * 4 + mt], cv.h, yacc[mt][nt], 0, 0, 0);
                }
            }
#pragma unroll
            for (int i = 0; i < 8; i++) kc[i] = kn[i];
        }
    }
    // store y^T C-frags: i = col, d = row -> float4 along d
#pragma unroll
    for (int mt = 0; mt < 4; mt++)
#pragma unroll
        for (int nt = 0; nt < 2; nt++) {
            fx4 s = yacc[mt][nt];
            float4 o; o.x = s[0]; o.y = s[1]; o.z = s[2]; o.w = s[3];
            *(float4*)&yout[(size_t)(bt0 + i0w + nt * 16 + l15) * 1024 + h * 64 + mt * 16 + qd * 4] = o;
        }
}

// ---------- groupnorm * g -> bf16 z (sums the two attention partials) ----------
__global__ __launch_bounds__(256) void k_gn(const float* __restrict__ y0,
                                            const float* __restrict__ y1,
                                            const float* __restrict__ g,
                                            const float* __restrict__ lnw,
                                            const float* __restrict__ lnb,
                                            unsigned short* __restrict__ z16) {
    int tid = threadIdx.x;
    int lane = tid & 63;
    int wv = tid >> 6;
    int group = blockIdx.x * 4 + wv;     // grid 16384
    int tok = group >> 4, h = group & 15;
    int d = h * 64 + lane;
    size_t idx = (size_t)tok * 1024 + d;
    float val = y0[idx] + y1[idx];
    float s = val, s2 = val * val;
#pragma unroll
    for (int off = 32; off > 0; off >>= 1) {
        s  += __shfl_xor(s, off, 64);
        s2 += __shfl_xor(s2, off, 64);
    }
    float mu = s * (1.f / 64.f);
    float var = s2 * (1.f / 64.f) - mu * mu;
    float inv = rsqrtf(var + 6.4e-4f);
    float yn = (val - mu) * inv * lnw[d] + lnb[d];
    z16[idx] = f2bf(yn * g[idx]);
}

extern "C" void kernel_launch(void* const* d_in, const int* in_sizes, int n_in,
                              void* d_out, int out_size, void* d_ws, size_t ws_size,
                              hipStream_t stream) {
    const float* x     = (const float*)d_in[0];
    const float* maa_x = (const float*)d_in[1];
    const float* maa_w = (const float*)d_in[2];
    const float* maa_k = (const float*)d_in[3];
    const float* maa_v = (const float*)d_in[4];
    const float* maa_r = (const float*)d_in[5];
    const float* maa_g = (const float*)d_in[6];
    const float* w1    = (const float*)d_in[7];
    const float* w2    = (const float*)d_in[8];
    const float* tdec  = (const float*)d_in[9];
    const float* dw1   = (const float*)d_in[10];
    const float* dw2   = (const float*)d_in[11];
    const float* W_r   = (const float*)d_in[12];
    const float* W_k   = (const float*)d_in[13];
    const float* W_v   = (const float*)d_in[14];
    const float* W_g   = (const float*)d_in[15];
    const float* W_o   = (const float*)d_in[16];
    const float* lnw   = (const float*)d_in[17];
    const float* lnb   = (const float*)d_in[18];

    float* ws = (float*)d_ws;
    size_t o = 0;
    float* dech   = ws + o; o += 262144;
    float* segsum = ws + o; o += 131072;
    float* ew     = ws + o; o += 4194304;
    float* cf     = ws + o; o += 4194304;
    float* cb     = ws + o; o += 4194304;
    float* gg     = ws + o; o += 4194304;
    unsigned short* us = (unsigned short*)(ws + o);
    size_t u = 0;
    unsigned short* xmix16 = us + u; u += 4194304;
    unsigned short* xw16 = us + u; u += 4194304;
    unsigned short* xr16 = us + u; u += 4194304;   // also z16 after gemm4
    unsigned short* xk16 = us + u; u += 4194304;
    unsigned short* xv16 = us + u; u += 4194304;
    unsigned short* xg16 = us + u; u += 4194304;
    unsigned short* qf   = us + u; u += 4194304;
    unsigned short* qb   = us + u; u += 4194304;
    unsigned short* kf   = us + u; u += 4194304;
    unsigned short* kb   = us + u; u += 4194304;
    unsigned short* vvt  = us + u; u += 4194304;
    unsigned short* Wrb  = us + u; u += 1048576;
    unsigned short* Wkb  = us + u; u += 1048576;
    unsigned short* Wvb  = us + u; u += 1048576;
    unsigned short* Wgb  = us + u; u += 1048576;
    unsigned short* Wob  = us + u; u += 1048576;
    unsigned short* w1T  = us + u; u += 163840;
    unsigned short* dw1T = us + u; u += 65536;
    unsigned short* xxx16 = us + u; u += 655360;
    unsigned short* w2T16 = us + u; u += 163840;
    float* yb0 = cf;               // attention partials reuse cf/cb (dead after gemm4)
    float* yb1 = cb;
    unsigned short* z16 = xr16;    // dead after gemm4

    k_prep<<<dim3(640, 7), 256, 0, stream>>>(W_r, W_k, W_v, W_g, W_o, w1, dw1, w2,
                                             Wrb, Wkb, Wvb, Wgb, Wob, w1T, dw1T, w2T16);
    k_mixx<<<4096, 256, 0, stream>>>(x, maa_x, xmix16);
    k_xxx2<<<256, 64, 0, stream>>>(xmix16, w1T, xxx16);
    k_mmix<<<dim3(16, 32), 256, 0, stream>>>(x, xxx16, w2T16, maa_w, maa_k, maa_v, maa_r, maa_g,
                                             xw16, xk16, xv16, xr16, xg16);
    k_dec1m<<<256, 64, 0, stream>>>(xw16, dw1T, dech);
    k_dec2<<<512, 256, 0, stream>>>(dech, dw2, tdec, ew);
    k_scan1<<<2048, 64, 0, stream>>>(ew, segsum);
    k_scan3<<<2048, 64, 0, stream>>>(ew, segsum, cf, cb);
    k_gemm4<<<dim3(256, 4), 256, 0, stream>>>(xr16, xk16, xv16, xg16, Wrb, Wkb, Wvb, Wgb,
                                              qf, qb, kf, kb, vvt, gg, cf, cb);
    k_attn<<<1024, 256, 0, stream>>>(qf, qb, kf, kb, vvt, yb0, yb1);
    k_gn<<<16384, 256, 0, stream>>>(yb0, yb1, gg, lnw, lnb, z16);
    k_gemmo<<<256, 256, 0, stream>>>(z16, Wob, (float*)d_out);
}

// Round 9
// 357.312 us; speedup vs baseline: 1.2831x; 1.1046x over previous
//
#include <hip/hip_runtime.h>
#include <math.h>

#define NB 4
#define TT 1024
#define DD 1024
#define NTOK 4096
#define ND (NTOK*DD)

typedef __attribute__((ext_vector_type(8))) short bh8;
typedef __attribute__((ext_vector_type(4))) float fx4;

__device__ __forceinline__ unsigned short f2bf(float f) {
    unsigned int b = __float_as_uint(f);
    b += 0x7fffu + ((b >> 16) & 1u);
    return (unsigned short)(b >> 16);
}

// pack two fp32 -> packed bf16 (RNE); HW v_cvt_pk_bf16_f32 when available
__device__ __forceinline__ unsigned pkbf(float a, float b) {
#if __has_builtin(__builtin_amdgcn_cvt_pk_bf16_f32)
    auto r = __builtin_amdgcn_cvt_pk_bf16_f32(a, b);
    unsigned u;
    __builtin_memcpy(&u, &r, 4);
    return u;
#else
    return ((unsigned)f2bf(b) << 16) | f2bf(a);
#endif
}

// async global->LDS, 16B per lane, LDS dst = wave-uniform base + lane*16
#define GLD16(gp, lp) __builtin_amdgcn_global_load_lds( \
    (__attribute__((address_space(1))) void*)(gp), \
    (__attribute__((address_space(3))) void*)(lp), 16, 0, 0)

// ---------- fused preprocessing: 5x wconv, w1T, dw1T, w2T ----------
__global__ __launch_bounds__(256) void k_prep(const float* __restrict__ W_r, const float* __restrict__ W_k,
                                              const float* __restrict__ W_v, const float* __restrict__ W_g,
                                              const float* __restrict__ W_o,
                                              const float* __restrict__ w1, const float* __restrict__ dw1,
                                              const float* __restrict__ w2,
                                              unsigned short* __restrict__ Wrb, unsigned short* __restrict__ Wkb,
                                              unsigned short* __restrict__ Wvb, unsigned short* __restrict__ Wgb,
                                              unsigned short* __restrict__ Wob,
                                              unsigned short* __restrict__ w1T, unsigned short* __restrict__ dw1T,
                                              unsigned short* __restrict__ w2T16) {
    int y = blockIdx.y, bx = blockIdx.x, tid = threadIdx.x;   // grid (640, 7)
    if (y < 5) {
        if (bx >= 512) return;
        const float* s = (y == 0) ? W_r : (y == 1) ? W_k : (y == 2) ? W_v : (y == 3) ? W_g : W_o;
        unsigned short* d = (y == 0) ? Wrb : (y == 1) ? Wkb : (y == 2) ? Wvb : (y == 3) ? Wgb : Wob;
        int i = (bx * 256 + tid) * 8;
        float4 a = *(const float4*)(s + i);
        float4 b = *(const float4*)(s + i + 4);
        uint4 o;
        o.x = pkbf(a.x, a.y);
        o.y = pkbf(a.z, a.w);
        o.z = pkbf(b.x, b.y);
        o.w = pkbf(b.z, b.w);
        *(uint4*)(d + i) = o;
    } else if (y == 5) {
        int o = bx * 256 + tid;          // 163840 total
        int r = o & 1023, c = o >> 10;
        w1T[o] = f2bf(w1[r * 160 + c]);
    } else {
        if (bx < 256) {
            int o = bx * 256 + tid;      // 65536 total
            int r = o & 1023, c = o >> 10;
            dw1T[o] = f2bf(dw1[r * 64 + c]);
        } else if (bx < 276) {
            int wi = bx - 256;
            int f = wi >> 2;
            int d = (wi & 3) * 256 + tid;
#pragma unroll 8
            for (int m = 0; m < 32; m++)
                w2T16[(size_t)(f * 1024 + d) * 32 + m] = f2bf(w2[(size_t)(f * 32 + m) * 1024 + d]);
        }
    }
}

// ---------- k1: xmix16 = bf16(x + dxprev * maa_x) ----------
__global__ __launch_bounds__(256) void k_mixx(const float* __restrict__ x,
                                              const float* __restrict__ maa_x,
                                              unsigned short* __restrict__ xmix16) {
    int base = (blockIdx.x * 256 + threadIdx.x) * 4;   // grid 4096
    int t = (base >> 10) & 1023;
    int d = base & 1023;
    float4 xv = *(const float4*)(x + base);
    float4 xm = (t > 0)    ? *(const float4*)(x + base - 1024) : make_float4(0, 0, 0, 0);
    float4 xp = (t < 1023) ? *(const float4*)(x + base + 1024) : make_float4(0, 0, 0, 0);
    float4 ma = *(const float4*)(maa_x + d);
    uint2 o;
    float a0 = xv.x + (0.5f * (xm.x + xp.x) - xv.x) * ma.x;
    float a1 = xv.y + (0.5f * (xm.y + xp.y) - xv.y) * ma.y;
    float a2 = xv.z + (0.5f * (xm.z + xp.z) - xv.z) * ma.z;
    float a3 = xv.w + (0.5f * (xm.w + xp.w) - xv.w) * ma.w;
    o.x = pkbf(a0, a1);
    o.y = pkbf(a2, a3);
    *(uint2*)(xmix16 + base) = o;
}

// ---------- k2: xxx16 = bf16(tanh(xmix @ w1)) via MFMA, 1-wave blocks ----------
__global__ __launch_bounds__(64) void k_xxx2(const unsigned short* __restrict__ xmix16,
                                             const unsigned short* __restrict__ w1T,
                                             unsigned short* __restrict__ xxx16) {
    int lane = threadIdx.x;
    int l15 = lane & 15, qd = lane >> 4;
    int m0 = blockIdx.x * 16;    // grid 256
    fx4 acc[10];
#pragma unroll
    for (int nt = 0; nt < 10; nt++)
#pragma unroll
        for (int r = 0; r < 4; r++) acc[nt][r] = 0.f;
#pragma unroll 2
    for (int kb = 0; kb < 1024; kb += 32) {
        bh8 af = *(const bh8*)(xmix16 + (size_t)(m0 + l15) * 1024 + kb + qd * 8);
#pragma unroll
        for (int nt = 0; nt < 10; nt++) {
            bh8 bf = *(const bh8*)(w1T + (size_t)(nt * 16 + l15) * 1024 + kb + qd * 8);
            acc[nt] = __builtin_amdgcn_mfma_f32_16x16x32_bf16(af, bf, acc[nt], 0, 0, 0);
        }
    }
#pragma unroll
    for (int nt = 0; nt < 10; nt++)
#pragma unroll
        for (int r = 0; r < 4; r++)
            xxx16[(size_t)(m0 + qd * 4 + r) * 160 + nt * 16 + l15] = f2bf(tanhf(acc[nt][r]));
}

// ---------- k3: fused mm-einsum (MFMA, K=32) + five mixes, no LDS ----------
__global__ __launch_bounds__(256, 2) void k_mmix(const float* __restrict__ x,
                                                 const unsigned short* __restrict__ xxx16,
                                                 const unsigned short* __restrict__ w2T16,
                                                 const float* __restrict__ maa_w,
                                                 const float* __restrict__ maa_k,
                                                 const float* __restrict__ maa_v,
                                                 const float* __restrict__ maa_r,
                                                 const float* __restrict__ maa_g,
                                                 unsigned short* __restrict__ xw16,
                                                 unsigned short* __restrict__ xk16,
                                                 unsigned short* __restrict__ xv16,
                                                 unsigned short* __restrict__ xr16,
                                                 unsigned short* __restrict__ xg16) {
    int tid = threadIdx.x;
    int w = tid >> 6, lane = tid & 63, l15 = lane & 15, qd = lane >> 4;
    int n0 = blockIdx.x * 64;               // grid (16, 32)
    int m0w = blockIdx.y * 128 + w * 32;
    const float* maap[5] = {maa_w, maa_k, maa_v, maa_r, maa_g};
    unsigned short* outp[5] = {xw16, xk16, xv16, xr16, xg16};
    float xin[8][4], dxv[8][4];
#pragma unroll
    for (int mi = 0; mi < 2; mi++)
#pragma unroll
        for (int r = 0; r < 4; r++) {
            int tok = m0w + mi * 16 + qd * 4 + r;
            int t = tok & 1023;
#pragma unroll
            for (int ni = 0; ni < 4; ni++) {
                int d = n0 + ni * 16 + l15;
                size_t idx = (size_t)tok * 1024 + d;
                float xv = x[idx];
                float xm1 = (t > 0)    ? x[idx - 1024] : 0.f;
                float xp1 = (t < 1023) ? x[idx + 1024] : 0.f;
                xin[mi * 4 + r][ni] = xv;
                dxv[mi * 4 + r][ni] = 0.5f * (xm1 + xp1) - xv;
            }
        }
#pragma unroll
    for (int f = 0; f < 5; f++) {
        bh8 af[2], bf[4];
#pragma unroll
        for (int mi = 0; mi < 2; mi++)
            af[mi] = *(const bh8*)(xxx16 + (size_t)(m0w + mi * 16 + l15) * 160 + f * 32 + qd * 8);
#pragma unroll
        for (int ni = 0; ni < 4; ni++)
            bf[ni] = *(const bh8*)(w2T16 + (size_t)(f * 1024 + n0 + ni * 16 + l15) * 32 + qd * 8);
        fx4 acc[2][4];
#pragma unroll
        for (int mi = 0; mi < 2; mi++)
#pragma unroll
            for (int ni = 0; ni < 4; ni++) {
#pragma unroll
                for (int r = 0; r < 4; r++) acc[mi][ni][r] = 0.f;
                acc[mi][ni] = __builtin_amdgcn_mfma_f32_16x16x32_bf16(af[mi], bf[ni], acc[mi][ni], 0, 0, 0);
            }
        const float* maa = maap[f];
        unsigned short* op = outp[f];
#pragma unroll
        for (int ni = 0; ni < 4; ni++) {
            float mv = maa[n0 + ni * 16 + l15];
#pragma unroll
            for (int mi = 0; mi < 2; mi++)
#pragma unroll
                for (int r = 0; r < 4; r++) {
                    float o = xin[mi * 4 + r][ni] + dxv[mi * 4 + r][ni] * (mv + acc[mi][ni][r]);
                    op[(size_t)(m0w + mi * 16 + qd * 4 + r) * 1024 + n0 + ni * 16 + l15] = f2bf(o);
                }
        }
    }
}

// ---------- decay GEMM1 via MFMA: dech = tanh(xw @ dw1), 1-wave blocks ----------
__global__ __launch_bounds__(64) void k_dec1m(const unsigned short* __restrict__ xw16,
                                              const unsigned short* __restrict__ dw1T,
                                              float* __restrict__ dech) {
    int lane = threadIdx.x;
    int l15 = lane & 15, qd = lane >> 4;
    int m0 = blockIdx.x * 16;    // grid 256
    fx4 acc[4];
#pragma unroll
    for (int nt = 0; nt < 4; nt++)
#pragma unroll
        for (int r = 0; r < 4; r++) acc[nt][r] = 0.f;
#pragma unroll 2
    for (int kb = 0; kb < 1024; kb += 32) {
        bh8 af = *(const bh8*)(xw16 + (size_t)(m0 + l15) * 1024 + kb + qd * 8);
#pragma unroll
        for (int nt = 0; nt < 4; nt++) {
            bh8 bf = *(const bh8*)(dw1T + (size_t)(nt * 16 + l15) * 1024 + kb + qd * 8);
            acc[nt] = __builtin_amdgcn_mfma_f32_16x16x32_bf16(af, bf, acc[nt], 0, 0, 0);
        }
    }
#pragma unroll
    for (int nt = 0; nt < 4; nt++)
#pragma unroll
        for (int r = 0; r < 4; r++)
            dech[(size_t)(m0 + qd * 4 + r) * 64 + nt * 16 + l15] = tanhf(acc[nt][r]);
}

// ---------- decay GEMM2: ew = -exp(time_decay + dech @ dw2) ----------
__global__ __launch_bounds__(256) void k_dec2(const float* __restrict__ dech,
                                              const float* __restrict__ dw2,
                                              const float* __restrict__ tdec,
                                              float* __restrict__ ew) {
    __shared__ float hl[8][64];
    int tid = threadIdx.x;
    int tok0 = blockIdx.x * 8;     // grid 512
    {
        int l = tid;        hl[l >> 6][l & 63] = dech[tok0 * 64 + l];
        l = tid + 256;      hl[l >> 6][l & 63] = dech[tok0 * 64 + l];
    }
    __syncthreads();
#pragma unroll 1
    for (int c = 0; c < 4; c++) {
        int d = c * 256 + tid;
        float acc[8] = {};
#pragma unroll 8
        for (int j = 0; j < 64; j++) {
            float wv = dw2[j * 1024 + d];
#pragma unroll
            for (int g = 0; g < 8; g++) acc[g] = fmaf(hl[g][j], wv, acc[g]);
        }
        float td = tdec[d];
#pragma unroll
        for (int g = 0; g < 8; g++) ew[(tok0 + g) * 1024 + d] = -expf(td + acc[g]);
    }
}

// ---------- scan stage 1: per-segment sums (seg = 32) ----------
__global__ __launch_bounds__(64) void k_scan1(const float* __restrict__ ew, float* __restrict__ segsum) {
    int bx = blockIdx.x;            // grid 2048 = 4b x 32seg x 16dch
    int b = bx >> 9, seg = (bx >> 4) & 31, dch = bx & 15;
    int d = dch * 64 + threadIdx.x;
    size_t base = ((size_t)(b * 1024 + seg * 32)) * 1024 + d;
    float s = 0.f;
#pragma unroll 8
    for (int t = 0; t < 32; t++) s += ew[base + (size_t)t * 1024];
    segsum[(b * 32 + seg) * 1024 + d] = s;
}

// ---------- scan stage 2+3 fused: local prefix of segsums + emit clipped cf/cb ----------
__global__ __launch_bounds__(64) void k_scan3(const float* __restrict__ ew, const float* __restrict__ segsum,
                                              float* __restrict__ cf, float* __restrict__ cb) {
    int bx = blockIdx.x;            // grid 2048
    int b = bx >> 9, seg = (bx >> 4) & 31, dch = bx & 15;
    int d = dch * 64 + threadIdx.x;
    float run = 0.f, pre = 0.f, off16 = 0.f;
#pragma unroll
    for (int s = 0; s < 32; s++) {
        float tv = segsum[(b * 32 + s) * 1024 + d];
        if (s == seg) pre = run;
        if (s == 16) off16 = run;
        run += tv;
    }
    float e512 = ew[((size_t)(b * 1024 + 512)) * 1024 + d];
    float sb = off16;           // cs[511]
    float sf = off16 + e512;    // cs[512]
    float cum = pre;
    size_t base = ((size_t)(b * 1024 + seg * 32)) * 1024 + d;
#pragma unroll 4
    for (int t = 0; t < 32; t++) {
        float prev = cum;
        cum += ew[base + (size_t)t * 1024];
        cf[base + (size_t)t * 1024] = fminf(fmaxf(cum - sf, -60.f), 60.f);
        cb[base + (size_t)t * 1024] = fminf(fmaxf(prev - sb, -60.f), 60.f);
    }
}

// ---------- bf16 MFMA GEMM core: C[4096][1024] = A @ W^T, async LDS staging ----------
// modes: 0 fp32 out, 1 silu fp32, 2 q-exp (O1=qf,O2=qb), 3 k-exp (O1=kf,O2=kb), 4 v-transpose (O1=vvt)
__device__ __forceinline__ void gemm_body(const unsigned short* __restrict__ A,
                                          const unsigned short* __restrict__ W,
                                          int m0, int n0, int mode,
                                          float* __restrict__ Cf,
                                          unsigned short* __restrict__ O1,
                                          unsigned short* __restrict__ O2,
                                          const float* __restrict__ cfp,
                                          const float* __restrict__ cbp,
                                          char* smem) {
    int tid = threadIdx.x;
    int w = tid >> 6, lane = tid & 63, l15 = lane & 15, qd = lane >> 4;
    int wm = w >> 1, wn = w & 1;
    fx4 acc[4][4];
#pragma unroll
    for (int mt = 0; mt < 4; mt++)
#pragma unroll
        for (int nt = 0; nt < 4; nt++)
#pragma unroll
            for (int r = 0; r < 4; r++) acc[mt][nt][r] = 0.f;
    unsigned short* sA = (unsigned short*)smem;            // [128][32]
    unsigned short* sB = (unsigned short*)(smem + 8192);   // [128][32]
    int rowA = tid >> 2, cA = tid & 3;
    for (int kb = 0; kb < 1024; kb += 32) {
        __syncthreads();
        GLD16(A + (size_t)(m0 + rowA) * 1024 + kb + cA * 8,      sA + w * 512);
        GLD16(A + (size_t)(m0 + 64 + rowA) * 1024 + kb + cA * 8, sA + 2048 + w * 512);
        GLD16(W + (size_t)(n0 + rowA) * 1024 + kb + cA * 8,      sB + w * 512);
        GLD16(W + (size_t)(n0 + 64 + rowA) * 1024 + kb + cA * 8, sB + 2048 + w * 512);
        __syncthreads();
        bh8 af[4], bfr[4];
#pragma unroll
        for (int mt = 0; mt < 4; mt++)
            af[mt] = *(const bh8*)(sA + (wm * 64 + mt * 16 + l15) * 32 + qd * 8);
#pragma unroll
        for (int nt = 0; nt < 4; nt++)
            bfr[nt] = *(const bh8*)(sB + (wn * 64 + nt * 16 + l15) * 32 + qd * 8);
#pragma unroll
        for (int mt = 0; mt < 4; mt++)
#pragma unroll
            for (int nt = 0; nt < 4; nt++)
                acc[mt][nt] = __builtin_amdgcn_mfma_f32_16x16x32_bf16(af[mt], bfr[nt], acc[mt][nt], 0, 0, 0);
    }
    int mb = m0 + wm * 64, nb = n0 + wn * 64;
    if (mode <= 1) {
#pragma unroll
        for (int mt = 0; mt < 4; mt++)
#pragma unroll
            for (int nt = 0; nt < 4; nt++) {
                fx4 s = acc[mt][nt];
#pragma unroll
                for (int r = 0; r < 4; r++) {
                    float v = s[r];
                    if (mode == 1) v = v / (1.f + __expf(-v));
                    Cf[(size_t)(mb + mt * 16 + qd * 4 + r) * 1024 + nb + nt * 16 + l15] = v;
                }
            }
    } else if (mode <= 3) {
        float s1 = (mode == 2) ? 1.f : -1.f;
#pragma unroll
        for (int mt = 0; mt < 4; mt++)
#pragma unroll
            for (int nt = 0; nt < 4; nt++) {
                fx4 s = acc[mt][nt];
#pragma unroll
                for (int r = 0; r < 4; r++) {
                    size_t idx = (size_t)(mb + mt * 16 + qd * 4 + r) * 1024 + nb + nt * 16 + l15;
                    float v = s[r];
                    O1[idx] = f2bf(v * __expf(s1 * cfp[idx]));
                    O2[idx] = f2bf(v * __expf(-s1 * cbp[idx]));
                }
            }
    } else {
        // transpose epilogue -> vvt[(b*1024 + d)][t]
        __syncthreads();
        unsigned short* T = (unsigned short*)smem;   // [128][136]
#pragma unroll
        for (int mt = 0; mt < 4; mt++)
#pragma unroll
            for (int nt = 0; nt < 4; nt++) {
                fx4 s = acc[mt][nt];
                int dl = wn * 64 + nt * 16 + l15;
                int tl = wm * 64 + mt * 16 + qd * 4;
                uint2 pk;
                pk.x = pkbf(s[0], s[1]);
                pk.y = pkbf(s[2], s[3]);
                *(uint2*)(T + dl * 136 + tl) = pk;
            }
        __syncthreads();
        int dl = tid >> 1, hf = tid & 1;
        int bq = m0 >> 10, t0 = m0 & 1023;
#pragma unroll
        for (int i = 0; i < 8; i++) {
            uint4 vv4 = *(const uint4*)(T + dl * 136 + hf * 64 + i * 8);
            *(uint4*)(O1 + (size_t)(bq * 1024 + n0 + dl) * 1024 + t0 + hf * 64 + i * 8) = vv4;
        }
    }
}

__global__ __launch_bounds__(256, 2) void k_gemm4(const unsigned short* __restrict__ xr16,
                                                  const unsigned short* __restrict__ xk16,
                                                  const unsigned short* __restrict__ xv16,
                                                  const unsigned short* __restrict__ xg16,
                                                  const unsigned short* __restrict__ Wrb,
                                                  const unsigned short* __restrict__ Wkb,
                                                  const unsigned short* __restrict__ Wvb,
                                                  const unsigned short* __restrict__ Wgb,
                                                  unsigned short* __restrict__ qf, unsigned short* __restrict__ qb,
                                                  unsigned short* __restrict__ kf, unsigned short* __restrict__ kb,
                                                  unsigned short* __restrict__ vvt,
                                                  float* __restrict__ gg,
                                                  const float* __restrict__ cf, const float* __restrict__ cb) {
    __shared__ __align__(16) char smem[34816];
    int m0 = (blockIdx.x >> 3) * 128, n0 = (blockIdx.x & 7) * 128;
    int y = blockIdx.y;
    if (y == 0)      gemm_body(xr16, Wrb, m0, n0, 2, nullptr, qf, qb, cf, cb, smem);
    else if (y == 1) gemm_body(xk16, Wkb, m0, n0, 3, nullptr, kf, kb, cf, cb, smem);
    else if (y == 2) gemm_body(xv16, Wvb, m0, n0, 4, nullptr, vvt, nullptr, nullptr, nullptr, smem);
    else             gemm_body(xg16, Wgb, m0, n0, 1, gg, nullptr, nullptr, nullptr, nullptr, smem);
}

__global__ __launch_bounds__(256, 2) void k_gemmo(const unsigned short* __restrict__ z16,
                                                  const unsigned short* __restrict__ Wob,
                                                  float* __restrict__ out) {
    __shared__ __align__(16) char smem[34816];
    gemm_body(z16, Wob, (blockIdx.x >> 3) * 128, (blockIdx.x & 7) * 128, 0, out,
              nullptr, nullptr, nullptr, nullptr, smem);
}

// ---------- attention: bidir LION, gemm-style LDS staging in fragment order ----------
__global__ __launch_bounds__(256, 2) void k_attn(const unsigned short* __restrict__ qf,
                                                 const unsigned short* __restrict__ qb,
                                                 const unsigned short* __restrict__ kf,
                                                 const unsigned short* __restrict__ kb,
                                                 const unsigned short* __restrict__ vvt,
                                                 float* __restrict__ y) {
    __shared__ __align__(16) char smem[16384];
    unsigned short* sK = (unsigned short*)smem;            // 8 frags x 1KB
    unsigned short* sV = (unsigned short*)(smem + 8192);   // 8 frags x 1KB
    int tid = threadIdx.x;
    int w = tid >> 6, lane = tid & 63, l15 = lane & 15, qd = lane >> 4;
    int bid = blockIdx.x;            // grid 512 = 64 bh x 8 itile, XCD-swizzled
    int bh = (bid & 7) + ((bid >> 6) << 3);
    int ib = (bid >> 3) & 7;
    int b = bh >> 4, h = bh & 15;
    int i0w = ib * 128 + w * 32;
    int bt0 = b * 1024;
    const unsigned short* vrow = vvt + (size_t)(b * 1024 + h * 64 + w * 16 + l15) * 1024 + qd * 8;
    int fmax = (i0w + 31) >> 6;       // last forward chunk this wave computes
    int bmin = i0w >> 6;              // first backward chunk this wave computes
    int srcA = l15 + ((lane & 16) << 1);   // l15 + 32*(qd&1)
    int srcB = srcA + 16;
    fx4 yacc[4][2];                   // [mt over d][nt over i]
#pragma unroll
    for (int mt = 0; mt < 4; mt++)
#pragma unroll
        for (int nt = 0; nt < 2; nt++)
#pragma unroll
            for (int r = 0; r < 4; r++) yacc[mt][nt][r] = 0.f;

    for (int phase = 0; phase < 2; phase++) {
        const unsigned short* Q = phase ? qb : qf;
        const unsigned short* K = phase ? kb : kf;
        bh8 qfr[2][2];
#pragma unroll
        for (int nt = 0; nt < 2; nt++)
#pragma unroll
            for (int ks = 0; ks < 2; ks++)
                qfr[nt][ks] = *(const bh8*)(Q + (size_t)(bt0 + i0w + nt * 16 + l15) * 1024
                                              + h * 64 + ks * 32 + qd * 8);
        int jlo = phase == 0 ? 0 : 2 * ib;            // block-uniform chunk range
        int jhi = phase == 0 ? 2 * ib + 1 : 15;
        const unsigned short* krow = K + (size_t)(bt0 + w * 16 + l15) * 1024 + h * 64 + qd * 8;
        for (int jt = jlo; jt <= jhi; jt++) {
            int jb = jt * 64;
            __syncthreads();
            // stage K tile + V^T tile in MFMA-fragment order (frag fi=ks*4+mt, 1KB each)
            GLD16(krow + (size_t)jb * 1024,        sK + w * 512);          // ks=0, mt=w
            GLD16(krow + (size_t)jb * 1024 + 32,   sK + 2048 + w * 512);   // ks=1, mt=w
            GLD16(vrow + jb,                        sV + w * 512);
            GLD16(vrow + jb + 32,                   sV + 2048 + w * 512);
            __syncthreads();
            bool active = (phase == 0) ? (jt <= fmax) : (jt >= bmin);
            if (!active) continue;
            bool needmask = (phase == 0) ? (jb + 63 > i0w) : (i0w + 31 >= jb);
            // QK: S^T tile (64j x 32i), A = K frags from LDS, B = Q regs
            bh8 kc[8];
#pragma unroll
            for (int fi = 0; fi < 8; fi++)
                kc[fi] = *(const bh8*)(sK + fi * 512 + lane * 8);
            fx4 sacc[4][2];
#pragma unroll
            for (int mt = 0; mt < 4; mt++)
#pragma unroll
                for (int nt = 0; nt < 2; nt++)
#pragma unroll
                    for (int r = 0; r < 4; r++) sacc[mt][nt][r] = 0.f;
#pragma unroll
            for (int ks = 0; ks < 2; ks++)
#pragma unroll
                for (int mt = 0; mt < 4; mt++)
#pragma unroll
                    for (int nt = 0; nt < 2; nt++)
                        sacc[mt][nt] = __builtin_amdgcn_mfma_f32_16x16x32_bf16(kc[ks * 4 + mt], qfr[nt][ks], sacc[mt][nt], 0, 0, 0);
            // mask + pack bf16
            uint2 pk[4][2];
#pragma unroll
            for (int mt = 0; mt < 4; mt++)
#pragma unroll
                for (int nt = 0; nt < 2; nt++) {
                    fx4 s = sacc[mt][nt];
                    if (needmask) {
                        int ii = i0w + nt * 16 + l15;
                        int jj0 = jb + mt * 16 + qd * 4;
#pragma unroll
                        for (int r = 0; r < 4; r++) {
                            bool keep = (phase == 0) ? (ii >= jj0 + r) : (ii < jj0 + r);
                            if (!keep) s[r] = 0.f;
                        }
                    }
                    pk[mt][nt].x = pkbf(s[0], s[1]);
                    pk[mt][nt].y = pkbf(s[2], s[3]);
                }
            // V frags from LDS
            bh8 vc[8];
#pragma unroll
            for (int fi = 0; fi < 8; fi++)
                vc[fi] = *(const bh8*)(sV + fi * 512 + lane * 8);
            // y^T += V^T * S^T : B = S^T frag via shfl redistribution
#pragma unroll
            for (int ks2 = 0; ks2 < 2; ks2++) {
#pragma unroll
                for (int nt = 0; nt < 2; nt++) {
                    int lox  = __shfl((int)pk[2 * ks2][nt].x,     srcA);
                    int hix  = __shfl((int)pk[2 * ks2 + 1][nt].x, srcA);
                    int loy  = __shfl((int)pk[2 * ks2][nt].y,     srcA);
                    int hiy  = __shfl((int)pk[2 * ks2 + 1][nt].y, srcA);
                    int lox2 = __shfl((int)pk[2 * ks2][nt].x,     srcB);
                    int hix2 = __shfl((int)pk[2 * ks2 + 1][nt].x, srcB);
                    int loy2 = __shfl((int)pk[2 * ks2][nt].y,     srcB);
                    int hiy2 = __shfl((int)pk[2 * ks2 + 1][nt].y, srcB);
                    union { int4 i; bh8 h; } cv;
                    cv.i.x = (qd & 2) ? hix  : lox;
                    cv.i.y = (qd & 2) ? hiy  : loy;
                    cv.i.z = (qd & 2) ? hix2 : lox2;
                    cv.i.w = (qd & 2) ? hiy2 : loy2;
#pragma unroll
                    for (int mt = 0; mt < 4; mt++)
                        yacc[mt][nt] = __builtin_amdgcn_mfma_f32_16x16x32_bf16(vc[ks2 * 4 + mt], cv.h, yacc[mt][nt], 0, 0, 0);
                }
            }
        }
    }
    // store y^T C-frags: i = col, d = row -> float4 along d
#pragma unroll
    for (int mt = 0; mt < 4; mt++)
#pragma unroll
        for (int nt = 0; nt < 2; nt++) {
            fx4 s = yacc[mt][nt];
            float4 o; o.x = s[0]; o.y = s[1]; o.z = s[2]; o.w = s[3];
            *(float4*)&y[(size_t)(bt0 + i0w + nt * 16 + l15) * 1024 + h * 64 + mt * 16 + qd * 4] = o;
        }
}

// ---------- groupnorm * g -> bf16 z ----------
__global__ __launch_bounds__(256) void k_gn(const float* __restrict__ y,
                                            const float* __restrict__ g,
                                            const float* __restrict__ lnw,
                                            const float* __restrict__ lnb,
                                            unsigned short* __restrict__ z16) {
    int tid = threadIdx.x;
    int lane = tid & 63;
    int wv = tid >> 6;
    int group = blockIdx.x * 4 + wv;     // grid 16384
    int tok = group >> 4, h = group & 15;
    int d = h * 64 + lane;
    size_t idx = (size_t)tok * 1024 + d;
    float val = y[idx];
    float s = val, s2 = val * val;
#pragma unroll
    for (int off = 32; off > 0; off >>= 1) {
        s  += __shfl_xor(s, off, 64);
        s2 += __shfl_xor(s2, off, 64);
    }
    float mu = s * (1.f / 64.f);
    float var = s2 * (1.f / 64.f) - mu * mu;
    float inv = rsqrtf(var + 6.4e-4f);
    float yn = (val - mu) * inv * lnw[d] + lnb[d];
    z16[idx] = f2bf(yn * g[idx]);
}

extern "C" void kernel_launch(void* const* d_in, const int* in_sizes, int n_in,
                              void* d_out, int out_size, void* d_ws, size_t ws_size,
                              hipStream_t stream) {
    const float* x     = (const float*)d_in[0];
    const float* maa_x = (const float*)d_in[1];
    const float* maa_w = (const float*)d_in[2];
    const float* maa_k = (const float*)d_in[3];
    const float* maa_v = (const float*)d_in[4];
    const float* maa_r = (const float*)d_in[5];
    const float* maa_g = (const float*)d_in[6];
    const float* w1    = (const float*)d_in[7];
    const float* w2    = (const float*)d_in[8];
    const float* tdec  = (const float*)d_in[9];
    const float* dw1   = (const float*)d_in[10];
    const float* dw2   = (const float*)d_in[11];
    const float* W_r   = (const float*)d_in[12];
    const float* W_k   = (const float*)d_in[13];
    const float* W_v   = (const float*)d_in[14];
    const float* W_g   = (const float*)d_in[15];
    const float* W_o   = (const float*)d_in[16];
    const float* lnw   = (const float*)d_in[17];
    const float* lnb   = (const float*)d_in[18];

    float* ws = (float*)d_ws;
    size_t o = 0;
    float* dech   = ws + o; o += 262144;
    float* segsum = ws + o; o += 131072;
    float* ew     = ws + o; o += 4194304;
    float* cf     = ws + o; o += 4194304;
    float* cb     = ws + o; o += 4194304;
    float* gg     = ws + o; o += 4194304;
    unsigned short* us = (unsigned short*)(ws + o);
    size_t u = 0;
    unsigned short* xmix16 = us + u; u += 4194304;
    unsigned short* xw16 = us + u; u += 4194304;
    unsigned short* xr16 = us + u; u += 4194304;   // also z16 after gemm4
    unsigned short* xk16 = us + u; u += 4194304;
    unsigned short* xv16 = us + u; u += 4194304;
    unsigned short* xg16 = us + u; u += 4194304;
    unsigned short* qf   = us + u; u += 4194304;
    unsigned short* qb   = us + u; u += 4194304;
    unsigned short* kf   = us + u; u += 4194304;
    unsigned short* kb   = us + u; u += 4194304;
    unsigned short* vvt  = us + u; u += 4194304;
    unsigned short* Wrb  = us + u; u += 1048576;
    unsigned short* Wkb  = us + u; u += 1048576;
    unsigned short* Wvb  = us + u; u += 1048576;
    unsigned short* Wgb  = us + u; u += 1048576;
    unsigned short* Wob  = us + u; u += 1048576;
    unsigned short* w1T  = us + u; u += 163840;
    unsigned short* dw1T = us + u; u += 65536;
    unsigned short* xxx16 = us + u; u += 655360;
    unsigned short* w2T16 = us + u; u += 163840;
    float* yb0 = cf;               // attention output reuses cf (dead after gemm4)
    unsigned short* z16 = xr16;    // dead after gemm4

    k_prep<<<dim3(640, 7), 256, 0, stream>>>(W_r, W_k, W_v, W_g, W_o, w1, dw1, w2,
                                             Wrb, Wkb, Wvb, Wgb, Wob, w1T, dw1T, w2T16);
    k_mixx<<<4096, 256, 0, stream>>>(x, maa_x, xmix16);
    k_xxx2<<<256, 64, 0, stream>>>(xmix16, w1T, xxx16);
    k_mmix<<<dim3(16, 32), 256, 0, stream>>>(x, xxx16, w2T16, maa_w, maa_k, maa_v, maa_r, maa_g,
                                             xw16, xk16, xv16, xr16, xg16);
    k_dec1m<<<256, 64, 0, stream>>>(xw16, dw1T, dech);
    k_dec2<<<512, 256, 0, stream>>>(dech, dw2, tdec, ew);
    k_scan1<<<2048, 64, 0, stream>>>(ew, segsum);
    k_scan3<<<2048, 64, 0, stream>>>(ew, segsum, cf, cb);
    k_gemm4<<<dim3(256, 4), 256, 0, stream>>>(xr16, xk16, xv16, xg16, Wrb, Wkb, Wvb, Wgb,
                                              qf, qb, kf, kb, vvt, gg, cf, cb);
    k_attn<<<512, 256, 0, stream>>>(qf, qb, kf, kb, vvt, yb0);
    k_gn<<<16384, 256, 0, stream>>>(yb0, gg, lnw, lnb, z16);
    k_gemmo<<<256, 256, 0, stream>>>(z16, Wob, (float*)d_out);
}